// Round 2
// baseline (1316.669 us; speedup 1.0000x reference)
//
#include <hip/hip_runtime.h>
#include <math.h>

#define LL 2048
#define MM 12
#define DD 128
#define TP 256   // T

// ---------------- embedding: strided conv1d (stride 8, K=16, pad 4/4) ----------------
__global__ __launch_bounds__(256) void k_emb(const float* __restrict__ inp, const float* __restrict__ ew,
                                             const float* __restrict__ eb, float* __restrict__ xe) {
  int sig = blockIdx.x;
  int b = sig / MM, m = sig % MM;
  __shared__ float xs[LL];
  const float* ib = inp + (size_t)b * LL * MM + m;
  for (int i = threadIdx.x; i < LL; i += 256) xs[i] = ib[(size_t)i * MM];
  __syncthreads();
  int t = threadIdx.x;
  int l0 = t * 8 - 4;
  float xv[16];
#pragma unroll
  for (int p = 0; p < 16; ++p) {
    int l = l0 + p;
    xv[p] = (l >= 0 && l < LL) ? xs[l] : 0.0f;
  }
  float* out = xe + (size_t)sig * DD * TP + t;
  for (int d = 0; d < DD; ++d) {
    float acc = eb[d];
#pragma unroll
    for (int p = 0; p < 16; ++p) acc += xv[p] * ew[d * 16 + p];
    out[(size_t)d * TP] = acc;
  }
}

// ---------------- fused block: dwconv(K=5)+GELU -> pointwise 128x128 GEMM + column-sum ----------------
// LDS plan (floats): us[128][36] @0 (aliased by pwT[32][132] after v computed),
//                    vt[128][36] @4608, dws[640] @9216, dwbs[128] @9856, sred[128][8] @9984
__global__ __launch_bounds__(256) void k_blk(const float* __restrict__ u, const float* __restrict__ dww,
                                             const float* __restrict__ dwb, const float* __restrict__ pw,
                                             const float* __restrict__ pwb, float* __restrict__ wout,
                                             float* __restrict__ sbuf) {
  __shared__ float smem[11008];
  float* us  = smem;            // 128*36
  float* pwT = smem;            // 32*132 (alias, used after us dead)
  float* vt  = smem + 4608;     // 128*36 (only [.][0..31] used)
  float* dws = smem + 9216;     // 640
  float* dwbs= smem + 9856;     // 128
  float* sred= smem + 9984;     // 128*8

  int sig = blockIdx.x >> 3;
  int t0 = (blockIdx.x & 7) * 32;
  int tid = threadIdx.x;

  // stage dw weights
  for (int i = tid; i < 640; i += 256) dws[i] = dww[i];
  if (tid < 128) dwbs[tid] = dwb[tid];

  // stage u tile with halo: us[d][j] = u[sig][d][t0-2+j], j=0..35
  const float* ub = u + (size_t)sig * DD * TP;
  for (int idx = tid; idx < 4608; idx += 256) {
    int d = idx / 36, j = idx - d * 36;
    int t = t0 - 2 + j;
    us[idx] = (t >= 0 && t < TP) ? ub[(size_t)d * TP + t] : 0.0f;
  }
  __syncthreads();

  // compute v = gelu(dwconv(u)) into vt[128][32]
  for (int idx = tid; idx < 4096; idx += 256) {
    int d = idx >> 5, tl = idx & 31;
    const float* ur = &us[d * 36 + tl];
    float acc = dwbs[d];
#pragma unroll
    for (int k = 0; k < 5; ++k) acc += ur[k] * dws[d * 5 + k];
    vt[d * 36 + tl] = 0.5f * acc * (1.0f + erff(acc * 0.70710678118654752f));
  }
  __syncthreads();

  // pointwise GEMM: w[e][t] = sum_d pw[e][d]*v[d][t]
  int eg = tid >> 3, tg = tid & 7;
  int e0 = eg * 4, tb = tg * 4;
  float acc[4][4];
#pragma unroll
  for (int j = 0; j < 4; ++j)
#pragma unroll
    for (int i = 0; i < 4; ++i) acc[j][i] = 0.0f;

  for (int dc = 0; dc < 4; ++dc) {
    int d0 = dc * 32;
    __syncthreads();
    // stage pwT[di][e] = pw[e][d0+di]
    for (int idx = tid; idx < 4096; idx += 256) {
      int di = idx & 31, e = idx >> 5;
      pwT[di * 132 + e] = pw[e * DD + d0 + di];
    }
    __syncthreads();
#pragma unroll
    for (int di = 0; di < 32; ++di) {
      float4 p4 = *(const float4*)&pwT[di * 132 + e0];
      float4 v4 = *(const float4*)&vt[(d0 + di) * 36 + tb];
      float pv[4] = {p4.x, p4.y, p4.z, p4.w};
      float vv[4] = {v4.x, v4.y, v4.z, v4.w};
#pragma unroll
      for (int j = 0; j < 4; ++j)
#pragma unroll
        for (int i = 0; i < 4; ++i) acc[j][i] += pv[j] * vv[i];
    }
  }

  // epilogue: bias, partial sums, store
  float* wbase = wout + (size_t)sig * DD * TP + t0;
#pragma unroll
  for (int j = 0; j < 4; ++j) {
    float bb = pwb[e0 + j];
    float ssum = 0.0f;
#pragma unroll
    for (int i = 0; i < 4; ++i) { acc[j][i] += bb; ssum += acc[j][i]; }
    sred[(e0 + j) * 8 + tg] = ssum;
    float4 w4 = {acc[j][0], acc[j][1], acc[j][2], acc[j][3]};
    *(float4*)&wbase[(size_t)(e0 + j) * TP + tb] = w4;
  }
  __syncthreads();
  if (tid < 128) {
    float tot = 0.0f;
#pragma unroll
    for (int g = 0; g < 8; ++g) tot += sred[tid * 8 + g];
    atomicAdd(&sbuf[sig * DD + tid], tot);
  }
}

// ---------------- block: SE gate ----------------
__global__ __launch_bounds__(128) void k_se(const float* __restrict__ sbuf, const float* __restrict__ w1,
                                            const float* __restrict__ b1, const float* __restrict__ w2,
                                            const float* __restrict__ b2, float* __restrict__ abuf) {
  int sig = blockIdx.x;
  __shared__ float sm[128];
  __shared__ float hh[32];
  int tid = threadIdx.x;
  sm[tid] = sbuf[sig * 128 + tid] * (1.0f / 256.0f);
  __syncthreads();
  if (tid < 32) {
    float acc = b1[tid];
    for (int d = 0; d < 128; ++d) acc += w1[tid * 128 + d] * sm[d];
    hh[tid] = fmaxf(acc, 0.0f);
  }
  __syncthreads();
  float acc = b2[tid];
#pragma unroll
  for (int r = 0; r < 32; ++r) acc += w2[tid * 32 + r] * hh[r];
  abuf[sig * 128 + tid] = 1.0f / (1.0f + expf(-acc));
}

// ---------------- block: u += w * a ----------------
__global__ __launch_bounds__(256) void k_upd(float* __restrict__ u, const float* __restrict__ w,
                                             const float* __restrict__ abuf) {
  size_t i = (size_t)blockIdx.x * 256 + threadIdx.x;  // float4 index
  int sig = (int)(i >> 13);
  int d = (int)((i >> 6) & 127);
  float a = abuf[sig * 128 + d];
  float4 uv = ((float4*)u)[i];
  float4 wv = ((const float4*)w)[i];
  uv.x += wv.x * a; uv.y += wv.y * a; uv.z += wv.z * a; uv.w += wv.w * a;
  ((float4*)u)[i] = uv;
}

// ---------------- final update + mean over M + layout change to (b,t,d) ----------------
__global__ __launch_bounds__(256) void k_reduce2(const float* __restrict__ u, const float* __restrict__ w,
                                                 const float* __restrict__ abuf, float* __restrict__ xe2) {
  size_t i = (size_t)blockIdx.x * 256 + threadIdx.x;  // over 64*128*256
  int t = (int)(i & 255);
  int d = (int)((i >> 8) & 127);
  int b = (int)(i >> 15);
  float acc = 0.0f;
  size_t base = (size_t)b * 12 * 32768 + d * 256 + t;
#pragma unroll
  for (int m = 0; m < 12; ++m) {
    float a = abuf[(b * 12 + m) * 128 + d];
    acc += u[base + (size_t)m * 32768] + w[base + (size_t)m * 32768] * a;
  }
  xe2[(size_t)b * 32768 + t * 128 + d] = acc * (1.0f / 12.0f);
}

// ---------------- small transpose dst[c*rows+r] = src[r*cols+c] ----------------
__global__ __launch_bounds__(256) void k_transpose(const float* __restrict__ src, float* __restrict__ dst,
                                                   int rows, int cols) {
  int i = blockIdx.x * 256 + threadIdx.x;
  if (i < rows * cols) {
    int r = i / cols, c = i % cols;
    dst[c * rows + r] = src[i];
  }
}

// ---------------- mamba: in-projection xz[b,t,e] = sum_d in_w[e,d] x[b,t,d] ----------------
__global__ __launch_bounds__(256) void k_inproj(const float* __restrict__ xe2, const float* __restrict__ inwT,
                                                float* __restrict__ xz) {
  int b = blockIdx.x >> 4;
  int t0 = (blockIdx.x & 15) * 16;
  __shared__ float xT[128][16];
  int tid = threadIdx.x;
  for (int idx = tid; idx < 2048; idx += 256) {
    int t = idx >> 7, d = idx & 127;
    xT[d][t] = xe2[(size_t)b * 32768 + (size_t)(t0 + t) * 128 + d];
  }
  __syncthreads();
  int eg = tid >> 1, tg = tid & 1;
  int e0 = eg * 4, ts = tg * 8;
  float acc[4][8];
#pragma unroll
  for (int j = 0; j < 4; ++j)
#pragma unroll
    for (int i = 0; i < 8; ++i) acc[j][i] = 0.0f;
#pragma unroll 4
  for (int d = 0; d < 128; ++d) {
    float4 wv = *(const float4*)&inwT[d * 512 + e0];
    float4 xa = *(const float4*)&xT[d][ts];
    float4 xb = *(const float4*)&xT[d][ts + 4];
    float xv[8] = {xa.x, xa.y, xa.z, xa.w, xb.x, xb.y, xb.z, xb.w};
    float wvv[4] = {wv.x, wv.y, wv.z, wv.w};
#pragma unroll
    for (int j = 0; j < 4; ++j)
#pragma unroll
      for (int i = 0; i < 8; ++i) acc[j][i] += wvv[j] * xv[i];
  }
#pragma unroll
  for (int i = 0; i < 8; ++i) {
    float4 o = {acc[0][i], acc[1][i], acc[2][i], acc[3][i]};
    *(float4*)&xz[(size_t)b * 256 * 512 + (size_t)(t0 + ts + i) * 512 + e0] = o;
  }
}

// ---------------- mamba: causal depthwise conv (K=4) + SiLU ----------------
__global__ __launch_bounds__(256) void k_convsilu(const float* __restrict__ xz, const float* __restrict__ cw,
                                                  const float* __restrict__ cb, float* __restrict__ xc) {
  size_t i = (size_t)blockIdx.x * 256 + threadIdx.x;  // 64*256*256
  int c = (int)(i & 255);
  int t = (int)((i >> 8) & 255);
  int b = (int)(i >> 16);
  const float* zb = xz + (size_t)b * 256 * 512 + c;
  float4 w4 = *(const float4*)&cw[c * 4];
  float wv[4] = {w4.x, w4.y, w4.z, w4.w};
  float acc = cb[c];
#pragma unroll
  for (int k = 0; k < 4; ++k) {
    int tt = t - 3 + k;
    if (tt >= 0) acc += zb[(size_t)tt * 512] * wv[k];
  }
  xc[i] = acc / (1.0f + expf(-acc));
}

// ---------------- mamba: x-projection (40 x 256) ----------------
__global__ __launch_bounds__(256) void k_xproj(const float* __restrict__ xc, const float* __restrict__ xw,
                                               float* __restrict__ dbl) {
  int b = blockIdx.x >> 3;
  int t0 = (blockIdx.x & 7) * 32;
  __shared__ float xT[256][33];
  int tid = threadIdx.x;
  for (int idx = tid; idx < 32 * 256; idx += 256) {
    int t = idx >> 8, c = idx & 255;
    xT[c][t] = xc[(size_t)b * 65536 + (size_t)(t0 + t) * 256 + c];
  }
  __syncthreads();
  int t = tid & 31, k0 = tid >> 5;
  for (int k = k0; k < 40; k += 8) {
    float acc = 0.0f;
    for (int c = 0; c < 256; ++c) acc += xw[k * 256 + c] * xT[c][t];
    dbl[(size_t)b * 256 * 40 + (size_t)(t0 + t) * 40 + k] = acc;
  }
}

// ---------------- mamba: fused dt + selective scan + y-finalize ----------------
// block: 16 channels x 16 states; chunks of 32 timesteps staged in LDS
__global__ __launch_bounds__(256) void k_scan2(const float* __restrict__ dbl, const float* __restrict__ xc,
                                               const float* __restrict__ xz, const float* __restrict__ Alog,
                                               const float* __restrict__ dtw, const float* __restrict__ dtbv,
                                               const float* __restrict__ Dp, float* __restrict__ y) {
  __shared__ float ds[32][40];   // dbl chunk
  __shared__ float xcs[32][16];
  __shared__ float zs[32][16];
  __shared__ float dts[32][16];
  __shared__ float yl[32][16];

  int b = blockIdx.x >> 4;
  int c0 = (blockIdx.x & 15) * 16;
  int tid = threadIdx.x;
  int ci = tid >> 4, s = tid & 15;
  int c = c0 + ci;

  float A = -expf(Alog[c * 16 + s]);
  float Dpc = Dp[c];
  float h = 0.0f;

  const float* dbp = dbl + (size_t)b * 10240;
  const float* xcp = xc + (size_t)b * 65536;
  const float* xzp = xz + (size_t)b * 131072;
  float* yp = y + (size_t)b * 65536;

  for (int chk = 0; chk < 8; ++chk) {
    int t0 = chk * 32;
    // stage dbl chunk (contiguous 1280 floats)
    for (int idx = tid; idx < 1280; idx += 256) ((float*)ds)[idx] = dbp[t0 * 40 + idx];
    // stage xc and z chunks
    for (int idx = tid; idx < 512; idx += 256) {
      int t = idx >> 4, cc = idx & 15;
      xcs[t][cc] = xcp[(size_t)(t0 + t) * 256 + c0 + cc];
      zs[t][cc] = xzp[(size_t)(t0 + t) * 512 + 256 + c0 + cc];
    }
    __syncthreads();
    // dt = softplus(dtw @ dbl[:, :8] + dtb)
    for (int idx = tid; idx < 512; idx += 256) {
      int t = idx >> 4, cc = idx & 15;
      int cg = c0 + cc;
      float4 wa = *(const float4*)&dtw[cg * 8];
      float4 wb = *(const float4*)&dtw[cg * 8 + 4];
      float acc = dtbv[cg];
      acc += wa.x * ds[t][0] + wa.y * ds[t][1] + wa.z * ds[t][2] + wa.w * ds[t][3]
           + wb.x * ds[t][4] + wb.y * ds[t][5] + wb.z * ds[t][6] + wb.w * ds[t][7];
      dts[t][cc] = (acc > 20.0f) ? acc : log1pf(expf(acc));
    }
    __syncthreads();
    // scan
    for (int t = 0; t < 32; ++t) {
      float dtv = dts[t][ci];
      float xcv = xcs[t][ci];
      float Bv = ds[t][8 + s];
      float Cv = ds[t][24 + s];
      h = __expf(dtv * A) * h + dtv * Bv * xcv;
      float p = h * Cv;
      p += __shfl_xor(p, 1, 64);
      p += __shfl_xor(p, 2, 64);
      p += __shfl_xor(p, 4, 64);
      p += __shfl_xor(p, 8, 64);
      if (s == 0) {
        float zv = zs[t][ci];
        float sz = zv / (1.0f + expf(-zv));
        yl[t][ci] = (p + Dpc * xcv) * sz;
      }
    }
    __syncthreads();
    // write out
    for (int idx = tid; idx < 512; idx += 256) {
      int t = idx >> 4, cc = idx & 15;
      yp[(size_t)(t0 + t) * 256 + c0 + cc] = yl[t][cc];
    }
    __syncthreads();
  }
}

// ---------------- mamba: out-projection + residual + LayerNorm (in place on xe2) ----------------
__global__ __launch_bounds__(256) void k_outln(const float* __restrict__ y, const float* __restrict__ owT,
                                               float* __restrict__ xe2, const float* __restrict__ g,
                                               const float* __restrict__ bb) {
  int b = blockIdx.x >> 5;
  int t0 = (blockIdx.x & 31) * 8;
  __shared__ float yl[8][256];
  __shared__ float rl[8][129];
  __shared__ float mus[8], rvs[8];
  int tid = threadIdx.x;
  for (int idx = tid; idx < 8 * 256; idx += 256) {
    int t = idx >> 8, c = idx & 255;
    yl[t][c] = y[(size_t)b * 65536 + (size_t)(t0 + t) * 256 + c];
  }
  __syncthreads();
  int d = tid & 127, tg = tid >> 7;
  float acc[4] = {0.f, 0.f, 0.f, 0.f};
  for (int e = 0; e < 256; ++e) {
    float w = owT[e * 128 + d];
#pragma unroll
    for (int i = 0; i < 4; ++i) acc[i] += w * yl[tg * 4 + i][e];
  }
#pragma unroll
  for (int i = 0; i < 4; ++i) {
    int t = tg * 4 + i;
    float r = xe2[(size_t)b * 32768 + (size_t)(t0 + t) * 128 + d] + acc[i];
    rl[t][d] = r;
  }
  __syncthreads();
  int rt = tid >> 5, j = tid & 31;
  float s1 = 0.f, s2 = 0.f;
#pragma unroll
  for (int q = 0; q < 4; ++q) {
    float vv = rl[rt][j + q * 32];
    s1 += vv; s2 += vv * vv;
  }
#pragma unroll
  for (int m = 1; m <= 16; m <<= 1) {
    s1 += __shfl_xor(s1, m, 64);
    s2 += __shfl_xor(s2, m, 64);
  }
  if (j == 0) {
    float mu = s1 * (1.0f / 128.0f);
    float var = s2 * (1.0f / 128.0f) - mu * mu;
    mus[rt] = mu;
    rvs[rt] = rsqrtf(var + 1e-5f);
  }
  __syncthreads();
#pragma unroll
  for (int i = 0; i < 4; ++i) {
    int t = tg * 4 + i;
    float val = (rl[t][d] - mus[t]) * rvs[t] * g[d] + bb[d];
    xe2[(size_t)b * 32768 + (size_t)(t0 + t) * 128 + d] = val;
  }
}

// ---------------- xflat transpose: out[b, d*256+t] = xe2[b, t*128+d] ----------------
__global__ __launch_bounds__(256) void k_xflat(const float* __restrict__ xe2, float* __restrict__ out) {
  int b = blockIdx.x >> 5;
  int blk = blockIdx.x & 31;
  int t0 = (blk >> 2) * 32, d0 = (blk & 3) * 32;
  __shared__ float tile[32][33];
  int tid = threadIdx.x;
#pragma unroll
  for (int q = 0; q < 4; ++q) {
    int t = (tid >> 5) + q * 8, dd = tid & 31;
    tile[t][dd] = xe2[(size_t)b * 32768 + (size_t)(t0 + t) * 128 + d0 + dd];
  }
  __syncthreads();
#pragma unroll
  for (int q = 0; q < 4; ++q) {
    int dd = (tid >> 5) + q * 8, t = tid & 31;
    out[(size_t)b * 32768 + (size_t)(d0 + dd) * 256 + t0 + t] = tile[t][dd];
  }
}

// ---------------- final FC ----------------
__global__ __launch_bounds__(256) void k_fc(const float* __restrict__ xflat, const float* __restrict__ fw,
                                            const float* __restrict__ fb, float* __restrict__ pred) {
  int b = blockIdx.x;
  int tid = threadIdx.x;
  float acc[18];
#pragma unroll
  for (int c = 0; c < 18; ++c) acc[c] = 0.0f;
  const float* xb = xflat + (size_t)b * 32768;
  for (int i = tid * 4; i < 32768; i += 1024) {
    float4 xv = *(const float4*)&xb[i];
#pragma unroll
    for (int c = 0; c < 18; ++c) {
      float4 wv = *(const float4*)&fw[(size_t)c * 32768 + i];
      acc[c] += xv.x * wv.x + xv.y * wv.y + xv.z * wv.z + xv.w * wv.w;
    }
  }
  __shared__ float red[256];
  for (int c = 0; c < 18; ++c) {
    red[tid] = acc[c];
    __syncthreads();
    for (int off = 128; off > 0; off >>= 1) {
      if (tid < off) red[tid] += red[tid + off];
      __syncthreads();
    }
    if (tid == 0) pred[b * 18 + c] = red[0] + fb[c];
    __syncthreads();
  }
}

extern "C" void kernel_launch(void* const* d_in, const int* in_sizes, int n_in,
                              void* d_out, int out_size, void* d_ws, size_t ws_size,
                              hipStream_t stream) {
  (void)in_sizes; (void)n_in; (void)out_size; (void)ws_size;
  const float* inp    = (const float*)d_in[0];
  const float* emb_w  = (const float*)d_in[1];
  const float* emb_b  = (const float*)d_in[2];
  const float* dw_w   = (const float*)d_in[3];
  const float* dw_b   = (const float*)d_in[4];
  const float* pw_w   = (const float*)d_in[5];
  const float* pw_b   = (const float*)d_in[6];
  const float* se_w1  = (const float*)d_in[7];
  const float* se_b1  = (const float*)d_in[8];
  const float* se_w2  = (const float*)d_in[9];
  const float* se_b2  = (const float*)d_in[10];
  const float* in_w   = (const float*)d_in[11];
  const float* conv_w = (const float*)d_in[12];
  const float* conv_b = (const float*)d_in[13];
  const float* xp_w   = (const float*)d_in[14];
  const float* dt_w   = (const float*)d_in[15];
  const float* dt_b   = (const float*)d_in[16];
  const float* Alog   = (const float*)d_in[17];
  const float* Dp     = (const float*)d_in[18];
  const float* out_w  = (const float*)d_in[19];
  const float* ln_g   = (const float*)d_in[20];
  const float* ln_b   = (const float*)d_in[21];
  const float* fc_w   = (const float*)d_in[22];
  const float* fc_b   = (const float*)d_in[23];

  char* ws = (char*)d_ws;
  float* bufA = (float*)ws;                    // 25165824 floats (xe / u)
  float* bufB = (float*)(ws + 100663296);      // 25165824 floats (w)
  float* sbuf = (float*)(ws + 201326592);      // 98304 floats
  float* abuf = sbuf + 98304;                  // 98304 floats
  // mamba-stage carve (bufA/bufB free after k_reduce2):
  float* xz   = bufA;                 // 8388608
  float* xc   = bufA + 8388608;       // 4194304
  float* yb   = bufA + 20971520;      // 4194304
  float* xe2  = bufB;                 // 2097152
  float* dbl  = bufB + 2097152;       // 655360
  float* inwT = bufB + 2752512;       // 65536
  float* owT  = bufB + 2818048;       // 32768

  float* xflat = (float*)d_out;
  float* pred  = xflat + (size_t)64 * 32768;

  k_emb<<<768, 256, 0, stream>>>(inp, emb_w, emb_b, bufA);

  for (int i = 0; i < 3; ++i) {
    hipMemsetAsync(sbuf, 0, 98304 * sizeof(float), stream);
    k_blk<<<6144, 256, 0, stream>>>(bufA, dw_w + i * 640, dw_b + i * 128,
                                    pw_w + i * 16384, pw_b + i * 128, bufB, sbuf);
    k_se<<<768, 128, 0, stream>>>(sbuf, se_w1 + i * 4096, se_b1 + i * 32,
                                  se_w2 + i * 4096, se_b2 + i * 128, abuf);
    if (i < 2) k_upd<<<24576, 256, 0, stream>>>(bufA, bufB, abuf);
  }

  k_reduce2<<<8192, 256, 0, stream>>>(bufA, bufB, abuf, xe2);

  for (int i = 0; i < 2; ++i) {
    k_transpose<<<256, 256, 0, stream>>>(in_w + i * 65536, inwT, 512, 128);
    k_transpose<<<128, 256, 0, stream>>>(out_w + i * 32768, owT, 128, 256);
    k_inproj<<<1024, 256, 0, stream>>>(xe2, inwT, xz);
    k_convsilu<<<16384, 256, 0, stream>>>(xz, conv_w + i * 1024, conv_b + i * 256, xc);
    k_xproj<<<512, 256, 0, stream>>>(xc, xp_w + i * 10240, dbl);
    k_scan2<<<1024, 256, 0, stream>>>(dbl, xc, xz, Alog + i * 4096,
                                      dt_w + i * 2048, dt_b + i * 256, Dp + i * 256, yb);
    k_outln<<<2048, 256, 0, stream>>>(yb, owT, xe2, ln_g + i * 128, ln_b + i * 128);
  }

  k_xflat<<<2048, 256, 0, stream>>>(xe2, xflat);
  k_fc<<<64, 256, 0, stream>>>(xflat, fc_w, fc_b, pred);
}

// Round 3
// 1221.691 us; speedup vs baseline: 1.0777x; 1.0777x over previous
//
#include <hip/hip_runtime.h>
#include <math.h>

#define LL 2048
#define MM 12
#define DD 128
#define TP 256   // T

typedef short short8 __attribute__((ext_vector_type(8)));
typedef float float4v __attribute__((ext_vector_type(4)));

static __device__ __forceinline__ unsigned short f2b(float f) {
  union { float f; unsigned int u; } x; x.f = f;
  unsigned int r = x.u + 0x7fffu + ((x.u >> 16) & 1u);
  return (unsigned short)(r >> 16);
}
static __device__ __forceinline__ float b2f(unsigned short u) {
  union { unsigned int u; float f; } x; x.u = ((unsigned int)u) << 16;
  return x.f;
}

// ---------------- convert pw weights (3 layers) to bf16 ----------------
__global__ __launch_bounds__(256) void k_cvt(const float* __restrict__ src, unsigned short* __restrict__ dst,
                                             int n) {
  int i = blockIdx.x * 256 + threadIdx.x;
  if (i < n) dst[i] = f2b(src[i]);
}

// ---------------- embedding: strided conv1d (stride 8, K=16, pad 4/4) -> bf16 u ----------------
__global__ __launch_bounds__(256) void k_emb(const float* __restrict__ inp, const float* __restrict__ ew,
                                             const float* __restrict__ eb, unsigned short* __restrict__ xe) {
  int sig = blockIdx.x;
  int b = sig / MM, m = sig % MM;
  __shared__ float xs[LL];
  const float* ib = inp + (size_t)b * LL * MM + m;
  for (int i = threadIdx.x; i < LL; i += 256) xs[i] = ib[(size_t)i * MM];
  __syncthreads();
  int t = threadIdx.x;
  int l0 = t * 8 - 4;
  float xv[16];
#pragma unroll
  for (int p = 0; p < 16; ++p) {
    int l = l0 + p;
    xv[p] = (l >= 0 && l < LL) ? xs[l] : 0.0f;
  }
  unsigned short* out = xe + (size_t)sig * DD * TP + t;
  for (int d = 0; d < DD; ++d) {
    float acc = eb[d];
#pragma unroll
    for (int p = 0; p < 16; ++p) acc += xv[p] * ew[d * 16 + p];
    out[(size_t)d * TP] = f2b(acc);
  }
}

// ---------------- fused block: [optional SE-update] + dwconv(K=5)+GELU -> MFMA GEMM + col-sums ----------------
// tile: full 128 e x 64 t, K=128. 256 threads = 4 waves, wave w handles t-range [t0+16w, +16)
// LDS: us(bf16 128x68)@0, vT(bf16 64x136)@17408, dws@34816, dwbs@37376 ; wS(f32 128x66) overlays [0,33792)
template<int UPD>
__global__ __launch_bounds__(256) void k_blk(const unsigned short* __restrict__ uin,
                                             const unsigned short* __restrict__ win,
                                             const float* __restrict__ abuf,
                                             const float* __restrict__ dww, const float* __restrict__ dwb,
                                             const unsigned short* __restrict__ pwbf,
                                             const float* __restrict__ pwb,
                                             unsigned short* __restrict__ uout,
                                             unsigned short* __restrict__ wout,
                                             float* __restrict__ sbuf) {
  __shared__ float smemf[9600];  // 38400 B
  unsigned short* us = (unsigned short*)smemf;            // [128][68]
  unsigned short* vT = (unsigned short*)smemf + 17408/2 * 0 + 8704;  // [64][136] (elem offset 8704)
  float* dws  = smemf + 8704;   // 640 floats @byte 34816
  float* dwbs = smemf + 9344;   // 128 floats
  float* wS   = smemf;          // overlays us+vT, [128][66] f32

  int sig = blockIdx.x >> 2;
  int t0 = (blockIdx.x & 3) * 64;
  int tid = threadIdx.x;

  for (int i = tid; i < 640; i += 256) dws[i] = dww[i];
  if (tid < 128) dwbs[tid] = dwb[tid];

  // stage u (with halo +-2), fused SE-update if UPD, write back own region of u_new
  for (int idx = tid; idx < 8704; idx += 256) {
    int d = idx / 68, j = idx - d * 68;
    int tg = t0 - 2 + j;
    float un = 0.0f;
    if (tg >= 0 && tg < TP) {
      size_t gi = (size_t)sig * 32768 + (size_t)d * 256 + tg;
      un = b2f(uin[gi]);
      if (UPD) un += b2f(win[gi]) * abuf[sig * 128 + d];
    }
    unsigned short ub = f2b(un);
    us[idx] = ub;
    if (UPD && j >= 2 && j < 66) uout[(size_t)sig * 32768 + (size_t)d * 256 + (t0 + j - 2)] = ub;
  }
  __syncthreads();

  // v = gelu(dwconv(u_new)) -> vT[t][d] (bf16, transposed for B-frag b128 loads)
  for (int idx = tid; idx < 8192; idx += 256) {
    int d = idx >> 6, t = idx & 63;
    const unsigned short* ur = us + d * 68 + t;
    float acc = dwbs[d];
#pragma unroll
    for (int k = 0; k < 5; ++k) acc += b2f(ur[k]) * dws[d * 5 + k];
    float g = 0.5f * acc * (1.0f + erff(acc * 0.70710678118654752f));
    vT[t * 136 + d] = f2b(g);
  }
  __syncthreads();

  // MFMA GEMM: w[e][t] = sum_d pw[e][d] * v[d][t]   (m=e, n=t, k=d)
  int wv = tid >> 6;          // wave id -> t-subtile
  int ln = tid & 15;          // lane&15
  int q  = (tid >> 4) & 3;    // quad
  int tw = wv * 16;
  float4v acc[8];
#pragma unroll
  for (int et = 0; et < 8; ++et) acc[et] = (float4v){0.f, 0.f, 0.f, 0.f};

#pragma unroll
  for (int kc = 0; kc < 4; ++kc) {
    int d0 = kc * 32;
    short8 bfrag = *(const short8*)(vT + (tw + ln) * 136 + d0 + q * 8);
#pragma unroll
    for (int et = 0; et < 8; ++et) {
      short8 af = *(const short8*)(pwbf + (size_t)(et * 16 + ln) * 128 + d0 + q * 8);
      acc[et] = __builtin_amdgcn_mfma_f32_16x16x32_bf16(af, bfrag, acc[et], 0, 0, 0);
    }
  }
  __syncthreads();  // vT reads done before wS overlays

  // C/D layout: e = et*16 + q*4 + r, t = tw + ln
#pragma unroll
  for (int et = 0; et < 8; ++et)
#pragma unroll
    for (int r = 0; r < 4; ++r)
      wS[(et * 16 + q * 4 + r) * 66 + tw + ln] = acc[et][r];
  __syncthreads();

  // bias + bf16 store + per-e row sums (one wave per e-row per iteration)
  for (int idx = tid; idx < 8192; idx += 256) {
    int e = idx >> 6, t = idx & 63;
    float val = wS[e * 66 + t] + pwb[e];
    wout[(size_t)sig * 32768 + (size_t)e * 256 + t0 + t] = f2b(val);
    float s = val;
#pragma unroll
    for (int m = 1; m <= 32; m <<= 1) s += __shfl_xor(s, m, 64);
    if ((tid & 63) == 0) atomicAdd(&sbuf[sig * 128 + e], s);
  }
}

// ---------------- block: SE gate ----------------
__global__ __launch_bounds__(128) void k_se(const float* __restrict__ sbuf, const float* __restrict__ w1,
                                            const float* __restrict__ b1, const float* __restrict__ w2,
                                            const float* __restrict__ b2, float* __restrict__ abuf) {
  int sig = blockIdx.x;
  __shared__ float sm[128];
  __shared__ float hh[32];
  int tid = threadIdx.x;
  sm[tid] = sbuf[sig * 128 + tid] * (1.0f / 256.0f);
  __syncthreads();
  if (tid < 32) {
    float acc = b1[tid];
    for (int d = 0; d < 128; ++d) acc += w1[tid * 128 + d] * sm[d];
    hh[tid] = fmaxf(acc, 0.0f);
  }
  __syncthreads();
  float acc = b2[tid];
#pragma unroll
  for (int r = 0; r < 32; ++r) acc += w2[tid * 32 + r] * hh[r];
  abuf[sig * 128 + tid] = 1.0f / (1.0f + expf(-acc));
}

// ---------------- final update + mean over M + layout change to (b,t,d) fp32 ----------------
__global__ __launch_bounds__(256) void k_reduce2(const unsigned short* __restrict__ u,
                                                 const unsigned short* __restrict__ w,
                                                 const float* __restrict__ abuf, float* __restrict__ xe2) {
  size_t i = (size_t)blockIdx.x * 256 + threadIdx.x;  // over 64*128*256
  int t = (int)(i & 255);
  int d = (int)((i >> 8) & 127);
  int b = (int)(i >> 15);
  float acc = 0.0f;
  size_t base = (size_t)b * 12 * 32768 + d * 256 + t;
#pragma unroll
  for (int m = 0; m < 12; ++m) {
    float a = abuf[(b * 12 + m) * 128 + d];
    acc += b2f(u[base + (size_t)m * 32768]) + b2f(w[base + (size_t)m * 32768]) * a;
  }
  xe2[(size_t)b * 32768 + t * 128 + d] = acc * (1.0f / 12.0f);
}

// ---------------- small transpose dst[c*rows+r] = src[r*cols+c] ----------------
__global__ __launch_bounds__(256) void k_transpose(const float* __restrict__ src, float* __restrict__ dst,
                                                   int rows, int cols) {
  int i = blockIdx.x * 256 + threadIdx.x;
  if (i < rows * cols) {
    int r = i / cols, c = i % cols;
    dst[c * rows + r] = src[i];
  }
}

// ---------------- mamba: in-projection xz[b,t,e] = sum_d in_w[e,d] x[b,t,d] ----------------
__global__ __launch_bounds__(256) void k_inproj(const float* __restrict__ xe2, const float* __restrict__ inwT,
                                                float* __restrict__ xz) {
  int b = blockIdx.x >> 4;
  int t0 = (blockIdx.x & 15) * 16;
  __shared__ float xT[128][16];
  int tid = threadIdx.x;
  for (int idx = tid; idx < 2048; idx += 256) {
    int t = idx >> 7, d = idx & 127;
    xT[d][t] = xe2[(size_t)b * 32768 + (size_t)(t0 + t) * 128 + d];
  }
  __syncthreads();
  int eg = tid >> 1, tg = tid & 1;
  int e0 = eg * 4, ts = tg * 8;
  float acc[4][8];
#pragma unroll
  for (int j = 0; j < 4; ++j)
#pragma unroll
    for (int i = 0; i < 8; ++i) acc[j][i] = 0.0f;
#pragma unroll 4
  for (int d = 0; d < 128; ++d) {
    float4 wv = *(const float4*)&inwT[d * 512 + e0];
    float4 xa = *(const float4*)&xT[d][ts];
    float4 xb = *(const float4*)&xT[d][ts + 4];
    float xv[8] = {xa.x, xa.y, xa.z, xa.w, xb.x, xb.y, xb.z, xb.w};
    float wvv[4] = {wv.x, wv.y, wv.z, wv.w};
#pragma unroll
    for (int j = 0; j < 4; ++j)
#pragma unroll
      for (int i = 0; i < 8; ++i) acc[j][i] += wvv[j] * xv[i];
  }
#pragma unroll
  for (int i = 0; i < 8; ++i) {
    float4 o = {acc[0][i], acc[1][i], acc[2][i], acc[3][i]};
    *(float4*)&xz[(size_t)b * 256 * 512 + (size_t)(t0 + ts + i) * 512 + e0] = o;
  }
}

// ---------------- mamba: causal depthwise conv (K=4) + SiLU ----------------
__global__ __launch_bounds__(256) void k_convsilu(const float* __restrict__ xz, const float* __restrict__ cw,
                                                  const float* __restrict__ cb, float* __restrict__ xc) {
  size_t i = (size_t)blockIdx.x * 256 + threadIdx.x;  // 64*256*256
  int c = (int)(i & 255);
  int t = (int)((i >> 8) & 255);
  int b = (int)(i >> 16);
  const float* zb = xz + (size_t)b * 256 * 512 + c;
  float4 w4 = *(const float4*)&cw[c * 4];
  float wv[4] = {w4.x, w4.y, w4.z, w4.w};
  float acc = cb[c];
#pragma unroll
  for (int k = 0; k < 4; ++k) {
    int tt = t - 3 + k;
    if (tt >= 0) acc += zb[(size_t)tt * 512] * wv[k];
  }
  xc[i] = acc / (1.0f + expf(-acc));
}

// ---------------- mamba: x-projection (40 x 256) ----------------
__global__ __launch_bounds__(256) void k_xproj(const float* __restrict__ xc, const float* __restrict__ xw,
                                               float* __restrict__ dbl) {
  int b = blockIdx.x >> 3;
  int t0 = (blockIdx.x & 7) * 32;
  __shared__ float xT[256][33];
  int tid = threadIdx.x;
  for (int idx = tid; idx < 32 * 256; idx += 256) {
    int t = idx >> 8, c = idx & 255;
    xT[c][t] = xc[(size_t)b * 65536 + (size_t)(t0 + t) * 256 + c];
  }
  __syncthreads();
  int t = tid & 31, k0 = tid >> 5;
  for (int k = k0; k < 40; k += 8) {
    float acc = 0.0f;
    for (int c = 0; c < 256; ++c) acc += xw[k * 256 + c] * xT[c][t];
    dbl[(size_t)b * 256 * 40 + (size_t)(t0 + t) * 40 + k] = acc;
  }
}

// ---------------- mamba: fused dt + selective scan + y-finalize ----------------
__global__ __launch_bounds__(256) void k_scan2(const float* __restrict__ dbl, const float* __restrict__ xc,
                                               const float* __restrict__ xz, const float* __restrict__ Alog,
                                               const float* __restrict__ dtw, const float* __restrict__ dtbv,
                                               const float* __restrict__ Dp, float* __restrict__ y) {
  __shared__ float ds[32][40];
  __shared__ float xcs[32][16];
  __shared__ float zs[32][16];
  __shared__ float dts[32][16];
  __shared__ float yl[32][16];

  int b = blockIdx.x >> 4;
  int c0 = (blockIdx.x & 15) * 16;
  int tid = threadIdx.x;
  int ci = tid >> 4, s = tid & 15;
  int c = c0 + ci;

  float A = -expf(Alog[c * 16 + s]);
  float Dpc = Dp[c];
  float h = 0.0f;

  const float* dbp = dbl + (size_t)b * 10240;
  const float* xcp = xc + (size_t)b * 65536;
  const float* xzp = xz + (size_t)b * 131072;
  float* yp = y + (size_t)b * 65536;

  for (int chk = 0; chk < 8; ++chk) {
    int t0 = chk * 32;
    for (int idx = tid; idx < 1280; idx += 256) ((float*)ds)[idx] = dbp[t0 * 40 + idx];
    for (int idx = tid; idx < 512; idx += 256) {
      int t = idx >> 4, cc = idx & 15;
      xcs[t][cc] = xcp[(size_t)(t0 + t) * 256 + c0 + cc];
      zs[t][cc] = xzp[(size_t)(t0 + t) * 512 + 256 + c0 + cc];
    }
    __syncthreads();
    for (int idx = tid; idx < 512; idx += 256) {
      int t = idx >> 4, cc = idx & 15;
      int cg = c0 + cc;
      float4 wa = *(const float4*)&dtw[cg * 8];
      float4 wb = *(const float4*)&dtw[cg * 8 + 4];
      float acc = dtbv[cg];
      acc += wa.x * ds[t][0] + wa.y * ds[t][1] + wa.z * ds[t][2] + wa.w * ds[t][3]
           + wb.x * ds[t][4] + wb.y * ds[t][5] + wb.z * ds[t][6] + wb.w * ds[t][7];
      dts[t][cc] = (acc > 20.0f) ? acc : log1pf(expf(acc));
    }
    __syncthreads();
    for (int t = 0; t < 32; ++t) {
      float dtv = dts[t][ci];
      float xcv = xcs[t][ci];
      float Bv = ds[t][8 + s];
      float Cv = ds[t][24 + s];
      h = __expf(dtv * A) * h + dtv * Bv * xcv;
      float p = h * Cv;
      p += __shfl_xor(p, 1, 64);
      p += __shfl_xor(p, 2, 64);
      p += __shfl_xor(p, 4, 64);
      p += __shfl_xor(p, 8, 64);
      if (s == 0) {
        float zv = zs[t][ci];
        float sz = zv / (1.0f + expf(-zv));
        yl[t][ci] = (p + Dpc * xcv) * sz;
      }
    }
    __syncthreads();
    for (int idx = tid; idx < 512; idx += 256) {
      int t = idx >> 4, cc = idx & 15;
      yp[(size_t)(t0 + t) * 256 + c0 + cc] = yl[t][cc];
    }
    __syncthreads();
  }
}

// ---------------- mamba: out-projection + residual + LayerNorm (in place on xe2) ----------------
__global__ __launch_bounds__(256) void k_outln(const float* __restrict__ y, const float* __restrict__ owT,
                                               float* __restrict__ xe2, const float* __restrict__ g,
                                               const float* __restrict__ bb) {
  int b = blockIdx.x >> 5;
  int t0 = (blockIdx.x & 31) * 8;
  __shared__ float yl[8][256];
  __shared__ float rl[8][129];
  __shared__ float mus[8], rvs[8];
  int tid = threadIdx.x;
  for (int idx = tid; idx < 8 * 256; idx += 256) {
    int t = idx >> 8, c = idx & 255;
    yl[t][c] = y[(size_t)b * 65536 + (size_t)(t0 + t) * 256 + c];
  }
  __syncthreads();
  int d = tid & 127, tg = tid >> 7;
  float acc[4] = {0.f, 0.f, 0.f, 0.f};
  for (int e = 0; e < 256; ++e) {
    float w = owT[e * 128 + d];
#pragma unroll
    for (int i = 0; i < 4; ++i) acc[i] += w * yl[tg * 4 + i][e];
  }
#pragma unroll
  for (int i = 0; i < 4; ++i) {
    int t = tg * 4 + i;
    float r = xe2[(size_t)b * 32768 + (size_t)(t0 + t) * 128 + d] + acc[i];
    rl[t][d] = r;
  }
  __syncthreads();
  int rt = tid >> 5, j = tid & 31;
  float s1 = 0.f, s2 = 0.f;
#pragma unroll
  for (int q = 0; q < 4; ++q) {
    float vv = rl[rt][j + q * 32];
    s1 += vv; s2 += vv * vv;
  }
#pragma unroll
  for (int m = 1; m <= 16; m <<= 1) {
    s1 += __shfl_xor(s1, m, 64);
    s2 += __shfl_xor(s2, m, 64);
  }
  if (j == 0) {
    float mu = s1 * (1.0f / 128.0f);
    float var = s2 * (1.0f / 128.0f) - mu * mu;
    mus[rt] = mu;
    rvs[rt] = rsqrtf(var + 1e-5f);
  }
  __syncthreads();
#pragma unroll
  for (int i = 0; i < 4; ++i) {
    int t = tg * 4 + i;
    float val = (rl[t][d] - mus[t]) * rvs[t] * g[d] + bb[d];
    xe2[(size_t)b * 32768 + (size_t)(t0 + t) * 128 + d] = val;
  }
}

// ---------------- xflat transpose ----------------
__global__ __launch_bounds__(256) void k_xflat(const float* __restrict__ xe2, float* __restrict__ out) {
  int b = blockIdx.x >> 5;
  int blk = blockIdx.x & 31;
  int t0 = (blk >> 2) * 32, d0 = (blk & 3) * 32;
  __shared__ float tile[32][33];
  int tid = threadIdx.x;
#pragma unroll
  for (int q = 0; q < 4; ++q) {
    int t = (tid >> 5) + q * 8, dd = tid & 31;
    tile[t][dd] = xe2[(size_t)b * 32768 + (size_t)(t0 + t) * 128 + d0 + dd];
  }
  __syncthreads();
#pragma unroll
  for (int q = 0; q < 4; ++q) {
    int dd = (tid >> 5) + q * 8, t = tid & 31;
    out[(size_t)b * 32768 + (size_t)(d0 + dd) * 256 + t0 + t] = tile[t][dd];
  }
}

// ---------------- final FC ----------------
__global__ __launch_bounds__(256) void k_fc(const float* __restrict__ xflat, const float* __restrict__ fw,
                                            const float* __restrict__ fb, float* __restrict__ pred) {
  int b = blockIdx.x;
  int tid = threadIdx.x;
  float acc[18];
#pragma unroll
  for (int c = 0; c < 18; ++c) acc[c] = 0.0f;
  const float* xb = xflat + (size_t)b * 32768;
  for (int i = tid * 4; i < 32768; i += 1024) {
    float4 xv = *(const float4*)&xb[i];
#pragma unroll
    for (int c = 0; c < 18; ++c) {
      float4 wv = *(const float4*)&fw[(size_t)c * 32768 + i];
      acc[c] += xv.x * wv.x + xv.y * wv.y + xv.z * wv.z + xv.w * wv.w;
    }
  }
  __shared__ float red[256];
  for (int c = 0; c < 18; ++c) {
    red[tid] = acc[c];
    __syncthreads();
    for (int off = 128; off > 0; off >>= 1) {
      if (tid < off) red[tid] += red[tid + off];
      __syncthreads();
    }
    if (tid == 0) pred[b * 18 + c] = red[0] + fb[c];
    __syncthreads();
  }
}

extern "C" void kernel_launch(void* const* d_in, const int* in_sizes, int n_in,
                              void* d_out, int out_size, void* d_ws, size_t ws_size,
                              hipStream_t stream) {
  (void)in_sizes; (void)n_in; (void)out_size; (void)ws_size;
  const float* inp    = (const float*)d_in[0];
  const float* emb_w  = (const float*)d_in[1];
  const float* emb_b  = (const float*)d_in[2];
  const float* dw_w   = (const float*)d_in[3];
  const float* dw_b   = (const float*)d_in[4];
  const float* pw_w   = (const float*)d_in[5];
  const float* pw_b   = (const float*)d_in[6];
  const float* se_w1  = (const float*)d_in[7];
  const float* se_b1  = (const float*)d_in[8];
  const float* se_w2  = (const float*)d_in[9];
  const float* se_b2  = (const float*)d_in[10];
  const float* in_w   = (const float*)d_in[11];
  const float* conv_w = (const float*)d_in[12];
  const float* conv_b = (const float*)d_in[13];
  const float* xp_w   = (const float*)d_in[14];
  const float* dt_w   = (const float*)d_in[15];
  const float* dt_b   = (const float*)d_in[16];
  const float* Alog   = (const float*)d_in[17];
  const float* Dp     = (const float*)d_in[18];
  const float* out_w  = (const float*)d_in[19];
  const float* ln_g   = (const float*)d_in[20];
  const float* ln_b   = (const float*)d_in[21];
  const float* fc_w   = (const float*)d_in[22];
  const float* fc_b   = (const float*)d_in[23];

  char* ws = (char*)d_ws;
  // bf16 ping-pong buffers: 25165824 elems each (50331648 B)
  unsigned short* U0 = (unsigned short*)(ws);
  unsigned short* W0 = (unsigned short*)(ws + 50331648);
  unsigned short* U1 = (unsigned short*)(ws + 100663296);
  unsigned short* W1 = (unsigned short*)(ws + 150994944);
  float* sbuf = (float*)(ws + 201326592);      // 98304 floats
  float* abuf = sbuf + 98304;                  // 98304 floats
  // mamba carve (block buffers dead after reduce2):
  float* xz  = (float*)(ws);                   // 8388608 f  (U0 region)
  float* xc  = (float*)(ws + 33554432);        // 4194304 f
  float* yb  = (float*)(ws + 50331648);        // 4194304 f  (W0 region)
  float* xe2 = (float*)(ws + 100663296);       // 2097152 f  (U1 region)
  float* dbl = (float*)(ws + 150994944);       // 655360 f   (W1 region)
  float* inwT= (float*)(ws + 153616384);       // 65536 f
  float* owT = (float*)(ws + 153878528);       // 32768 f

  float* xflat = (float*)d_out;
  float* pred  = xflat + (size_t)64 * 32768;
  // bf16 pw weights live in d_out scratch until k_xflat overwrites it
  unsigned short* pwbf = (unsigned short*)d_out;  // 49152 elems (98304 B) << 8.4 MB

  k_cvt<<<192, 256, 0, stream>>>(pw_w, pwbf, 49152);
  k_emb<<<768, 256, 0, stream>>>(inp, emb_w, emb_b, U0);

  // L0: read U0 -> write W0 (no update)
  hipMemsetAsync(sbuf, 0, 98304 * sizeof(float), stream);
  k_blk<0><<<3072, 256, 0, stream>>>(U0, U0, abuf, dw_w, dw_b, pwbf, pw_b, U0, W0, sbuf);
  k_se<<<768, 128, 0, stream>>>(sbuf, se_w1, se_b1, se_w2, se_b2, abuf);
  // L1: read U0,W0,a0 -> write U1,W1
  hipMemsetAsync(sbuf, 0, 98304 * sizeof(float), stream);
  k_blk<1><<<3072, 256, 0, stream>>>(U0, W0, abuf, dw_w + 640, dw_b + 128, pwbf + 16384, pw_b + 128,
                                     U1, W1, sbuf);
  k_se<<<768, 128, 0, stream>>>(sbuf, se_w1 + 4096, se_b1 + 32, se_w2 + 4096, se_b2 + 128, abuf);
  // L2: read U1,W1,a1 -> write U0,W0
  hipMemsetAsync(sbuf, 0, 98304 * sizeof(float), stream);
  k_blk<1><<<3072, 256, 0, stream>>>(U1, W1, abuf, dw_w + 1280, dw_b + 256, pwbf + 32768, pw_b + 256,
                                     U0, W0, sbuf);
  k_se<<<768, 128, 0, stream>>>(sbuf, se_w1 + 8192, se_b1 + 64, se_w2 + 8192, se_b2 + 256, abuf);

  k_reduce2<<<8192, 256, 0, stream>>>(U0, W0, abuf, xe2);

  for (int i = 0; i < 2; ++i) {
    k_transpose<<<256, 256, 0, stream>>>(in_w + i * 65536, inwT, 512, 128);
    k_transpose<<<128, 256, 0, stream>>>(out_w + i * 32768, owT, 128, 256);
    k_inproj<<<1024, 256, 0, stream>>>(xe2, inwT, xz);
    k_convsilu<<<16384, 256, 0, stream>>>(xz, conv_w + i * 1024, conv_b + i * 256, xc);
    k_xproj<<<512, 256, 0, stream>>>(xc, xp_w + i * 10240, dbl);
    k_scan2<<<1024, 256, 0, stream>>>(dbl, xc, xz, Alog + i * 4096,
                                      dt_w + i * 2048, dt_b + i * 256, Dp + i * 256, yb);
    k_outln<<<2048, 256, 0, stream>>>(yb, owT, xe2, ln_g + i * 128, ln_b + i * 128);
  }

  k_xflat<<<2048, 256, 0, stream>>>(xe2, xflat);
  k_fc<<<64, 256, 0, stream>>>(xflat, fc_w, fc_b, pred);
}

// Round 4
// 928.330 us; speedup vs baseline: 1.4183x; 1.3160x over previous
//
#include <hip/hip_runtime.h>
#include <math.h>

#define LL 2048
#define MM 12
#define DD 128
#define TP 256   // T

typedef short short8 __attribute__((ext_vector_type(8)));
typedef short short4v __attribute__((ext_vector_type(4)));
typedef float float4v __attribute__((ext_vector_type(4)));

static __device__ __forceinline__ unsigned short f2b(float f) {
  union { float f; unsigned int u; } x; x.f = f;
  unsigned int r = x.u + 0x7fffu + ((x.u >> 16) & 1u);
  return (unsigned short)(r >> 16);
}
static __device__ __forceinline__ float b2f(unsigned short u) {
  union { unsigned int u; float f; } x; x.u = ((unsigned int)u) << 16;
  return x.f;
}

// ---------------- convert pw weights (3 layers) to bf16 ----------------
__global__ __launch_bounds__(256) void k_cvt(const float* __restrict__ src, unsigned short* __restrict__ dst,
                                             int n) {
  int i = blockIdx.x * 256 + threadIdx.x;
  if (i < n) dst[i] = f2b(src[i]);
}

// ---------------- embedding: strided conv1d (stride 8, K=16, pad 4/4) -> bf16 u[sig][t][d] ----------------
__global__ __launch_bounds__(256) void k_emb(const float* __restrict__ inp, const float* __restrict__ ew,
                                             const float* __restrict__ eb, unsigned short* __restrict__ xe) {
  int sig = blockIdx.x;
  int b = sig / MM, m = sig % MM;
  __shared__ float xs[LL];
  __shared__ float ews[DD * 17];  // padded stride 17
  __shared__ float ebs[DD];
  const float* ib = inp + (size_t)b * LL * MM + m;
  int tid = threadIdx.x;
  for (int i = tid; i < LL; i += 256) xs[i] = ib[(size_t)i * MM];
  for (int i = tid; i < DD * 16; i += 256) ews[(i >> 4) * 17 + (i & 15)] = ew[i];
  if (tid < DD) ebs[tid] = eb[tid];
  __syncthreads();
  int d0 = (tid & 15) * 8;
  for (int it = 0; it < 16; ++it) {
    int t = it * 16 + (tid >> 4);
    int l0 = t * 8 - 4;
    float acc[8];
#pragma unroll
    for (int j = 0; j < 8; ++j) acc[j] = ebs[d0 + j];
#pragma unroll
    for (int p = 0; p < 16; ++p) {
      int l = l0 + p;
      float xv = (l >= 0 && l < LL) ? xs[l] : 0.0f;
#pragma unroll
      for (int j = 0; j < 8; ++j) acc[j] += xv * ews[(d0 + j) * 17 + p];
    }
    short8 r;
#pragma unroll
    for (int j = 0; j < 8; ++j) r[j] = (short)f2b(acc[j]);
    *(short8*)(xe + (size_t)sig * 32768 + (size_t)t * 128 + d0) = r;
  }
}

// ---------------- fused block, layout [sig][t][d]:
// [SE-update] -> dwconv(K=5,along t)+GELU -> MFMA 128e x 64t x K128 -> direct frag stores + col sums
template<int UPD>
__global__ __launch_bounds__(256) void k_blk(const unsigned short* __restrict__ uin,
                                             const unsigned short* __restrict__ win,
                                             const float* __restrict__ abuf,
                                             const float* __restrict__ dww, const float* __restrict__ dwb,
                                             const unsigned short* __restrict__ pwbf,
                                             const float* __restrict__ pwb,
                                             unsigned short* __restrict__ uout,
                                             unsigned short* __restrict__ wout,
                                             float* __restrict__ sbuf) {
  __shared__ float smemf[10512];
  unsigned short* us = (unsigned short*)smemf;   // [68][136] bf16 (rows t0-2..t0+65)
  unsigned short* vT = us + 9248;                // [64][136] bf16
  float* dws  = smemf + 8976;                    // 640
  float* dwbs = smemf + 9616;                    // 128
  float* abufL= smemf + 9744;                    // 128
  float* pwbL = smemf + 9872;                    // 128
  float* sred = smemf + 10000;                   // 4*128

  int sig = blockIdx.x >> 2;
  int t0 = (blockIdx.x & 3) * 64;
  int tid = threadIdx.x;
  const size_t gbase = (size_t)sig * 32768;

  for (int i = tid; i < 640; i += 256) dws[i] = dww[i];
  if (tid < 128) {
    dwbs[tid] = dwb[tid];
    pwbL[tid] = pwb[tid];
    abufL[tid] = UPD ? abuf[sig * 128 + tid] : 0.0f;
  }
  __syncthreads();

  int c8 = (tid & 15) * 8;
  float aloc[8];
#pragma unroll
  for (int j = 0; j < 8; ++j) aloc[j] = abufL[c8 + j];

  // stage u tile (halo +-2) with fused SE-update; write back u_new
  const short8 ZV = {0, 0, 0, 0, 0, 0, 0, 0};
#pragma unroll
  for (int it = 0; it < 5; ++it) {
    int idx = it * 256 + tid;
    if (idx < 1088) {
      int row = idx >> 4;           // = it*16 + (tid>>4)
      int t = t0 - 2 + row;
      short8 u8 = ZV;
      if (t >= 0 && t < TP) {
        u8 = *(const short8*)(uin + gbase + (size_t)t * 128 + c8);
        if (UPD) {
          short8 w8 = *(const short8*)(win + gbase + (size_t)t * 128 + c8);
          short8 r;
#pragma unroll
          for (int j = 0; j < 8; ++j)
            r[j] = (short)f2b(b2f((unsigned short)u8[j]) + b2f((unsigned short)w8[j]) * aloc[j]);
          u8 = r;
          if (row >= 2 && row < 66)
            *(short8*)(uout + gbase + (size_t)(t0 + row - 2) * 128 + c8) = u8;
        }
      }
      *(short8*)(us + row * 136 + c8) = u8;
    }
  }
  __syncthreads();

  // dwconv along t + exact GELU -> vT[t][d]
  float wl[5][8], bl[8];
#pragma unroll
  for (int j = 0; j < 8; ++j) {
    bl[j] = dwbs[c8 + j];
#pragma unroll
    for (int k = 0; k < 5; ++k) wl[k][j] = dws[(c8 + j) * 5 + k];
  }
#pragma unroll
  for (int it = 0; it < 4; ++it) {
    int t = it * 16 + (tid >> 4);
    float acc[8];
#pragma unroll
    for (int j = 0; j < 8; ++j) acc[j] = bl[j];
#pragma unroll
    for (int k = 0; k < 5; ++k) {
      short8 u8 = *(const short8*)(us + (t + k) * 136 + c8);
#pragma unroll
      for (int j = 0; j < 8; ++j) acc[j] += b2f((unsigned short)u8[j]) * wl[k][j];
    }
    short8 r;
#pragma unroll
    for (int j = 0; j < 8; ++j) {
      float g = 0.5f * acc[j] * (1.0f + erff(acc[j] * 0.70710678118654752f));
      r[j] = (short)f2b(g);
    }
    *(short8*)(vT + t * 136 + c8) = r;
  }
  __syncthreads();

  // MFMA: w[e][t] = sum_d pw[e][d] * v[d][t]  (m=e, n=t, k=d)
  int wv = tid >> 6;
  int ln = tid & 15;
  int q  = (tid >> 4) & 3;
  int tw = wv * 16;
  float4v acc[8];
#pragma unroll
  for (int et = 0; et < 8; ++et) acc[et] = (float4v){0.f, 0.f, 0.f, 0.f};
#pragma unroll
  for (int kc = 0; kc < 4; ++kc) {
    int d0 = kc * 32;
    short8 bfrag = *(const short8*)(vT + (tw + ln) * 136 + d0 + q * 8);
#pragma unroll
    for (int et = 0; et < 8; ++et) {
      short8 af = *(const short8*)(pwbf + (size_t)(et * 16 + ln) * 128 + d0 + q * 8);
      acc[et] = __builtin_amdgcn_mfma_f32_16x16x32_bf16(af, bfrag, acc[et], 0, 0, 0);
    }
  }

  // direct frag stores (bias added) + in-register t-sums -> sred
  int tg = t0 + tw + ln;
#pragma unroll
  for (int et = 0; et < 8; ++et) {
    int e = et * 16 + q * 4;
    float v0 = acc[et][0] + pwbL[e];
    float v1 = acc[et][1] + pwbL[e + 1];
    float v2 = acc[et][2] + pwbL[e + 2];
    float v3 = acc[et][3] + pwbL[e + 3];
    short4v st = {(short)f2b(v0), (short)f2b(v1), (short)f2b(v2), (short)f2b(v3)};
    *(short4v*)(wout + gbase + (size_t)tg * 128 + e) = st;
    float s0 = v0, s1 = v1, s2 = v2, s3 = v3;
#pragma unroll
    for (int m = 1; m <= 8; m <<= 1) {
      s0 += __shfl_xor(s0, m, 64);
      s1 += __shfl_xor(s1, m, 64);
      s2 += __shfl_xor(s2, m, 64);
      s3 += __shfl_xor(s3, m, 64);
    }
    if (ln == 0) {
      float4v sv = {s0, s1, s2, s3};
      *(float4v*)&sred[wv * 128 + e] = sv;
    }
  }
  __syncthreads();
  if (tid < 128) {
    float tot = sred[tid] + sred[128 + tid] + sred[256 + tid] + sred[384 + tid];
    atomicAdd(&sbuf[sig * 128 + tid], tot);
  }
}

// ---------------- block: SE gate ----------------
__global__ __launch_bounds__(128) void k_se(const float* __restrict__ sbuf, const float* __restrict__ w1,
                                            const float* __restrict__ b1, const float* __restrict__ w2,
                                            const float* __restrict__ b2, float* __restrict__ abuf) {
  int sig = blockIdx.x;
  __shared__ float sm[128];
  __shared__ float hh[32];
  int tid = threadIdx.x;
  sm[tid] = sbuf[sig * 128 + tid] * (1.0f / 256.0f);
  __syncthreads();
  if (tid < 32) {
    float acc = b1[tid];
    for (int d = 0; d < 128; ++d) acc += w1[tid * 128 + d] * sm[d];
    hh[tid] = fmaxf(acc, 0.0f);
  }
  __syncthreads();
  float acc = b2[tid];
#pragma unroll
  for (int r = 0; r < 32; ++r) acc += w2[tid * 32 + r] * hh[r];
  abuf[sig * 128 + tid] = 1.0f / (1.0f + expf(-acc));
}

// ---------------- final update + mean over M -> xe2[b][t][d] fp32 ----------------
__global__ __launch_bounds__(256) void k_reduce2(const unsigned short* __restrict__ u,
                                                 const unsigned short* __restrict__ w,
                                                 const float* __restrict__ abuf, float* __restrict__ xe2) {
  int i = blockIdx.x * 256 + threadIdx.x;   // 262144 vec-units of 8
  int d0 = (i & 15) * 8;
  int t = (i >> 4) & 255;
  int b = i >> 12;
  float acc[8] = {0.f, 0.f, 0.f, 0.f, 0.f, 0.f, 0.f, 0.f};
#pragma unroll 4
  for (int m = 0; m < 12; ++m) {
    size_t base = ((size_t)(b * 12 + m) * 256 + t) * 128 + d0;
    short8 u8 = *(const short8*)(u + base);
    short8 w8 = *(const short8*)(w + base);
    float4 a0 = *(const float4*)&abuf[(b * 12 + m) * 128 + d0];
    float4 a1 = *(const float4*)&abuf[(b * 12 + m) * 128 + d0 + 4];
    float av[8] = {a0.x, a0.y, a0.z, a0.w, a1.x, a1.y, a1.z, a1.w};
#pragma unroll
    for (int j = 0; j < 8; ++j)
      acc[j] += b2f((unsigned short)u8[j]) + b2f((unsigned short)w8[j]) * av[j];
  }
  float* out = xe2 + (size_t)b * 32768 + (size_t)t * 128 + d0;
  float4 o0 = {acc[0] / 12.f, acc[1] / 12.f, acc[2] / 12.f, acc[3] / 12.f};
  float4 o1 = {acc[4] / 12.f, acc[5] / 12.f, acc[6] / 12.f, acc[7] / 12.f};
  *(float4*)out = o0;
  *(float4*)(out + 4) = o1;
}

// ---------------- small transpose dst[c*rows+r] = src[r*cols+c] ----------------
__global__ __launch_bounds__(256) void k_transpose(const float* __restrict__ src, float* __restrict__ dst,
                                                   int rows, int cols) {
  int i = blockIdx.x * 256 + threadIdx.x;
  if (i < rows * cols) {
    int r = i / cols, c = i % cols;
    dst[c * rows + r] = src[i];
  }
}

// ---------------- mamba: in-projection xz[b,t,e] = sum_d in_w[e,d] x[b,t,d] ----------------
__global__ __launch_bounds__(256) void k_inproj(const float* __restrict__ xe2, const float* __restrict__ inwT,
                                                float* __restrict__ xz) {
  int b = blockIdx.x >> 4;
  int t0 = (blockIdx.x & 15) * 16;
  __shared__ float xT[128][16];
  int tid = threadIdx.x;
  for (int idx = tid; idx < 2048; idx += 256) {
    int t = idx >> 7, d = idx & 127;
    xT[d][t] = xe2[(size_t)b * 32768 + (size_t)(t0 + t) * 128 + d];
  }
  __syncthreads();
  int eg = tid >> 1, tg = tid & 1;
  int e0 = eg * 4, ts = tg * 8;
  float acc[4][8];
#pragma unroll
  for (int j = 0; j < 4; ++j)
#pragma unroll
    for (int i = 0; i < 8; ++i) acc[j][i] = 0.0f;
#pragma unroll 4
  for (int d = 0; d < 128; ++d) {
    float4 wv = *(const float4*)&inwT[d * 512 + e0];
    float4 xa = *(const float4*)&xT[d][ts];
    float4 xb = *(const float4*)&xT[d][ts + 4];
    float xv[8] = {xa.x, xa.y, xa.z, xa.w, xb.x, xb.y, xb.z, xb.w};
    float wvv[4] = {wv.x, wv.y, wv.z, wv.w};
#pragma unroll
    for (int j = 0; j < 4; ++j)
#pragma unroll
      for (int i = 0; i < 8; ++i) acc[j][i] += wvv[j] * xv[i];
  }
#pragma unroll
  for (int i = 0; i < 8; ++i) {
    float4 o = {acc[0][i], acc[1][i], acc[2][i], acc[3][i]};
    *(float4*)&xz[(size_t)b * 256 * 512 + (size_t)(t0 + ts + i) * 512 + e0] = o;
  }
}

// ---------------- mamba: causal depthwise conv (K=4) + SiLU ----------------
__global__ __launch_bounds__(256) void k_convsilu(const float* __restrict__ xz, const float* __restrict__ cw,
                                                  const float* __restrict__ cb, float* __restrict__ xc) {
  size_t i = (size_t)blockIdx.x * 256 + threadIdx.x;  // 64*256*256
  int c = (int)(i & 255);
  int t = (int)((i >> 8) & 255);
  int b = (int)(i >> 16);
  const float* zb = xz + (size_t)b * 256 * 512 + c;
  float4 w4 = *(const float4*)&cw[c * 4];
  float wv[4] = {w4.x, w4.y, w4.z, w4.w};
  float acc = cb[c];
#pragma unroll
  for (int k = 0; k < 4; ++k) {
    int tt = t - 3 + k;
    if (tt >= 0) acc += zb[(size_t)tt * 512] * wv[k];
  }
  xc[i] = acc / (1.0f + expf(-acc));
}

// ---------------- mamba: x-projection (40 x 256) ----------------
__global__ __launch_bounds__(256) void k_xproj(const float* __restrict__ xc, const float* __restrict__ xw,
                                               float* __restrict__ dbl) {
  int b = blockIdx.x >> 3;
  int t0 = (blockIdx.x & 7) * 32;
  __shared__ float xT[256][33];
  int tid = threadIdx.x;
  for (int idx = tid; idx < 32 * 256; idx += 256) {
    int t = idx >> 8, c = idx & 255;
    xT[c][t] = xc[(size_t)b * 65536 + (size_t)(t0 + t) * 256 + c];
  }
  __syncthreads();
  int t = tid & 31, k0 = tid >> 5;
  for (int k = k0; k < 40; k += 8) {
    float acc = 0.0f;
    for (int c = 0; c < 256; ++c) acc += xw[k * 256 + c] * xT[c][t];
    dbl[(size_t)b * 256 * 40 + (size_t)(t0 + t) * 40 + k] = acc;
  }
}

// ---------------- mamba: fused dt + selective scan + y-finalize ----------------
__global__ __launch_bounds__(256) void k_scan2(const float* __restrict__ dbl, const float* __restrict__ xc,
                                               const float* __restrict__ xz, const float* __restrict__ Alog,
                                               const float* __restrict__ dtw, const float* __restrict__ dtbv,
                                               const float* __restrict__ Dp, float* __restrict__ y) {
  __shared__ float ds[32][40];
  __shared__ float xcs[32][16];
  __shared__ float zs[32][16];
  __shared__ float dts[32][16];
  __shared__ float yl[32][16];

  int b = blockIdx.x >> 4;
  int c0 = (blockIdx.x & 15) * 16;
  int tid = threadIdx.x;
  int ci = tid >> 4, s = tid & 15;
  int c = c0 + ci;

  float A = -expf(Alog[c * 16 + s]);
  float Dpc = Dp[c];
  float h = 0.0f;

  const float* dbp = dbl + (size_t)b * 10240;
  const float* xcp = xc + (size_t)b * 65536;
  const float* xzp = xz + (size_t)b * 131072;
  float* yp = y + (size_t)b * 65536;

  for (int chk = 0; chk < 8; ++chk) {
    int t0 = chk * 32;
    for (int idx = tid; idx < 1280; idx += 256) ((float*)ds)[idx] = dbp[t0 * 40 + idx];
    for (int idx = tid; idx < 512; idx += 256) {
      int t = idx >> 4, cc = idx & 15;
      xcs[t][cc] = xcp[(size_t)(t0 + t) * 256 + c0 + cc];
      zs[t][cc] = xzp[(size_t)(t0 + t) * 512 + 256 + c0 + cc];
    }
    __syncthreads();
    for (int idx = tid; idx < 512; idx += 256) {
      int t = idx >> 4, cc = idx & 15;
      int cg = c0 + cc;
      float4 wa = *(const float4*)&dtw[cg * 8];
      float4 wb = *(const float4*)&dtw[cg * 8 + 4];
      float acc = dtbv[cg];
      acc += wa.x * ds[t][0] + wa.y * ds[t][1] + wa.z * ds[t][2] + wa.w * ds[t][3]
           + wb.x * ds[t][4] + wb.y * ds[t][5] + wb.z * ds[t][6] + wb.w * ds[t][7];
      dts[t][cc] = (acc > 20.0f) ? acc : log1pf(expf(acc));
    }
    __syncthreads();
    for (int t = 0; t < 32; ++t) {
      float dtv = dts[t][ci];
      float xcv = xcs[t][ci];
      float Bv = ds[t][8 + s];
      float Cv = ds[t][24 + s];
      h = __expf(dtv * A) * h + dtv * Bv * xcv;
      float p = h * Cv;
      p += __shfl_xor(p, 1, 64);
      p += __shfl_xor(p, 2, 64);
      p += __shfl_xor(p, 4, 64);
      p += __shfl_xor(p, 8, 64);
      if (s == 0) {
        float zv = zs[t][ci];
        float sz = zv / (1.0f + expf(-zv));
        yl[t][ci] = (p + Dpc * xcv) * sz;
      }
    }
    __syncthreads();
    for (int idx = tid; idx < 512; idx += 256) {
      int t = idx >> 4, cc = idx & 15;
      yp[(size_t)(t0 + t) * 256 + c0 + cc] = yl[t][cc];
    }
    __syncthreads();
  }
}

// ---------------- mamba: out-projection + residual + LayerNorm (in place on xe2) ----------------
__global__ __launch_bounds__(256) void k_outln(const float* __restrict__ y, const float* __restrict__ owT,
                                               float* __restrict__ xe2, const float* __restrict__ g,
                                               const float* __restrict__ bb) {
  int b = blockIdx.x >> 5;
  int t0 = (blockIdx.x & 31) * 8;
  __shared__ float yl[8][256];
  __shared__ float rl[8][129];
  __shared__ float mus[8], rvs[8];
  int tid = threadIdx.x;
  for (int idx = tid; idx < 8 * 256; idx += 256) {
    int t = idx >> 8, c = idx & 255;
    yl[t][c] = y[(size_t)b * 65536 + (size_t)(t0 + t) * 256 + c];
  }
  __syncthreads();
  int d = tid & 127, tg = tid >> 7;
  float acc[4] = {0.f, 0.f, 0.f, 0.f};
  for (int e = 0; e < 256; ++e) {
    float w = owT[e * 128 + d];
#pragma unroll
    for (int i = 0; i < 4; ++i) acc[i] += w * yl[tg * 4 + i][e];
  }
#pragma unroll
  for (int i = 0; i < 4; ++i) {
    int t = tg * 4 + i;
    float r = xe2[(size_t)b * 32768 + (size_t)(t0 + t) * 128 + d] + acc[i];
    rl[t][d] = r;
  }
  __syncthreads();
  int rt = tid >> 5, j = tid & 31;
  float s1 = 0.f, s2 = 0.f;
#pragma unroll
  for (int q = 0; q < 4; ++q) {
    float vv = rl[rt][j + q * 32];
    s1 += vv; s2 += vv * vv;
  }
#pragma unroll
  for (int m = 1; m <= 16; m <<= 1) {
    s1 += __shfl_xor(s1, m, 64);
    s2 += __shfl_xor(s2, m, 64);
  }
  if (j == 0) {
    float mu = s1 * (1.0f / 128.0f);
    float var = s2 * (1.0f / 128.0f) - mu * mu;
    mus[rt] = mu;
    rvs[rt] = rsqrtf(var + 1e-5f);
  }
  __syncthreads();
#pragma unroll
  for (int i = 0; i < 4; ++i) {
    int t = tg * 4 + i;
    float val = (rl[t][d] - mus[t]) * rvs[t] * g[d] + bb[d];
    xe2[(size_t)b * 32768 + (size_t)(t0 + t) * 128 + d] = val;
  }
}

// ---------------- xflat transpose ----------------
__global__ __launch_bounds__(256) void k_xflat(const float* __restrict__ xe2, float* __restrict__ out) {
  int b = blockIdx.x >> 5;
  int blk = blockIdx.x & 31;
  int t0 = (blk >> 2) * 32, d0 = (blk & 3) * 32;
  __shared__ float tile[32][33];
  int tid = threadIdx.x;
#pragma unroll
  for (int q = 0; q < 4; ++q) {
    int t = (tid >> 5) + q * 8, dd = tid & 31;
    tile[t][dd] = xe2[(size_t)b * 32768 + (size_t)(t0 + t) * 128 + d0 + dd];
  }
  __syncthreads();
#pragma unroll
  for (int q = 0; q < 4; ++q) {
    int dd = (tid >> 5) + q * 8, t = tid & 31;
    out[(size_t)b * 32768 + (size_t)(d0 + dd) * 256 + t0 + t] = tile[t][dd];
  }
}

// ---------------- final FC ----------------
__global__ __launch_bounds__(256) void k_fc(const float* __restrict__ xflat, const float* __restrict__ fw,
                                            const float* __restrict__ fb, float* __restrict__ pred) {
  int b = blockIdx.x;
  int tid = threadIdx.x;
  float acc[18];
#pragma unroll
  for (int c = 0; c < 18; ++c) acc[c] = 0.0f;
  const float* xb = xflat + (size_t)b * 32768;
  for (int i = tid * 4; i < 32768; i += 1024) {
    float4 xv = *(const float4*)&xb[i];
#pragma unroll
    for (int c = 0; c < 18; ++c) {
      float4 wv = *(const float4*)&fw[(size_t)c * 32768 + i];
      acc[c] += xv.x * wv.x + xv.y * wv.y + xv.z * wv.z + xv.w * wv.w;
    }
  }
  __shared__ float red[256];
  for (int c = 0; c < 18; ++c) {
    red[tid] = acc[c];
    __syncthreads();
    for (int off = 128; off > 0; off >>= 1) {
      if (tid < off) red[tid] += red[tid + off];
      __syncthreads();
    }
    if (tid == 0) pred[b * 18 + c] = red[0] + fb[c];
    __syncthreads();
  }
}

extern "C" void kernel_launch(void* const* d_in, const int* in_sizes, int n_in,
                              void* d_out, int out_size, void* d_ws, size_t ws_size,
                              hipStream_t stream) {
  (void)in_sizes; (void)n_in; (void)out_size; (void)ws_size;
  const float* inp    = (const float*)d_in[0];
  const float* emb_w  = (const float*)d_in[1];
  const float* emb_b  = (const float*)d_in[2];
  const float* dw_w   = (const float*)d_in[3];
  const float* dw_b   = (const float*)d_in[4];
  const float* pw_w   = (const float*)d_in[5];
  const float* pw_b   = (const float*)d_in[6];
  const float* se_w1  = (const float*)d_in[7];
  const float* se_b1  = (const float*)d_in[8];
  const float* se_w2  = (const float*)d_in[9];
  const float* se_b2  = (const float*)d_in[10];
  const float* in_w   = (const float*)d_in[11];
  const float* conv_w = (const float*)d_in[12];
  const float* conv_b = (const float*)d_in[13];
  const float* xp_w   = (const float*)d_in[14];
  const float* dt_w   = (const float*)d_in[15];
  const float* dt_b   = (const float*)d_in[16];
  const float* Alog   = (const float*)d_in[17];
  const float* Dp     = (const float*)d_in[18];
  const float* out_w  = (const float*)d_in[19];
  const float* ln_g   = (const float*)d_in[20];
  const float* ln_b   = (const float*)d_in[21];
  const float* fc_w   = (const float*)d_in[22];
  const float* fc_b   = (const float*)d_in[23];

  char* ws = (char*)d_ws;
  unsigned short* U0 = (unsigned short*)(ws);
  unsigned short* W0 = (unsigned short*)(ws + 50331648);
  unsigned short* U1 = (unsigned short*)(ws + 100663296);
  unsigned short* W1 = (unsigned short*)(ws + 150994944);
  float* sbuf = (float*)(ws + 201326592);      // 98304 floats
  float* abuf = sbuf + 98304;                  // 98304 floats
  float* xz  = (float*)(ws);                   // 8388608 f  (U0 region)
  float* xc  = (float*)(ws + 33554432);        // 4194304 f
  float* yb  = (float*)(ws + 50331648);        // 4194304 f  (W0 region)
  float* xe2 = (float*)(ws + 100663296);       // 2097152 f  (U1 region)
  float* dbl = (float*)(ws + 150994944);       // 655360 f   (W1 region)
  float* inwT= (float*)(ws + 153616384);       // 65536 f
  float* owT = (float*)(ws + 153878528);       // 32768 f

  float* xflat = (float*)d_out;
  float* pred  = xflat + (size_t)64 * 32768;
  unsigned short* pwbf = (unsigned short*)d_out;  // scratch until k_xflat overwrites

  k_cvt<<<192, 256, 0, stream>>>(pw_w, pwbf, 49152);
  k_emb<<<768, 256, 0, stream>>>(inp, emb_w, emb_b, U0);

  hipMemsetAsync(sbuf, 0, 98304 * sizeof(float), stream);
  k_blk<0><<<3072, 256, 0, stream>>>(U0, U0, abuf, dw_w, dw_b, pwbf, pw_b, U0, W0, sbuf);
  k_se<<<768, 128, 0, stream>>>(sbuf, se_w1, se_b1, se_w2, se_b2, abuf);
  hipMemsetAsync(sbuf, 0, 98304 * sizeof(float), stream);
  k_blk<1><<<3072, 256, 0, stream>>>(U0, W0, abuf, dw_w + 640, dw_b + 128, pwbf + 16384, pw_b + 128,
                                     U1, W1, sbuf);
  k_se<<<768, 128, 0, stream>>>(sbuf, se_w1 + 4096, se_b1 + 32, se_w2 + 4096, se_b2 + 128, abuf);
  hipMemsetAsync(sbuf, 0, 98304 * sizeof(float), stream);
  k_blk<1><<<3072, 256, 0, stream>>>(U1, W1, abuf, dw_w + 1280, dw_b + 256, pwbf + 32768, pw_b + 256,
                                     U0, W0, sbuf);
  k_se<<<768, 128, 0, stream>>>(sbuf, se_w1 + 8192, se_b1 + 64, se_w2 + 8192, se_b2 + 256, abuf);

  k_reduce2<<<1024, 256, 0, stream>>>(U0, W0, abuf, xe2);

  for (int i = 0; i < 2; ++i) {
    k_transpose<<<256, 256, 0, stream>>>(in_w + i * 65536, inwT, 512, 128);
    k_transpose<<<128, 256, 0, stream>>>(out_w + i * 32768, owT, 128, 256);
    k_inproj<<<1024, 256, 0, stream>>>(xe2, inwT, xz);
    k_convsilu<<<16384, 256, 0, stream>>>(xz, conv_w + i * 1024, conv_b + i * 256, xc);
    k_xproj<<<512, 256, 0, stream>>>(xc, xp_w + i * 10240, dbl);
    k_scan2<<<1024, 256, 0, stream>>>(dbl, xc, xz, Alog + i * 4096,
                                      dt_w + i * 2048, dt_b + i * 256, Dp + i * 256, yb);
    k_outln<<<2048, 256, 0, stream>>>(yb, owT, xe2, ln_g + i * 128, ln_b + i * 128);
  }

  k_xflat<<<2048, 256, 0, stream>>>(xe2, xflat);
  k_fc<<<64, 256, 0, stream>>>(xflat, fc_w, fc_b, pred);
}

// Round 5
// 874.922 us; speedup vs baseline: 1.5049x; 1.0610x over previous
//
#include <hip/hip_runtime.h>
#include <math.h>

#define LL 2048
#define MM 12
#define DD 128
#define TP 256   // T

typedef short short8 __attribute__((ext_vector_type(8)));
typedef short short4v __attribute__((ext_vector_type(4)));
typedef float float4v __attribute__((ext_vector_type(4)));

static __device__ __forceinline__ unsigned short f2b(float f) {
  union { float f; unsigned int u; } x; x.f = f;
  unsigned int r = x.u + 0x7fffu + ((x.u >> 16) & 1u);
  return (unsigned short)(r >> 16);
}
static __device__ __forceinline__ float b2f(unsigned short u) {
  union { unsigned int u; float f; } x; x.u = ((unsigned int)u) << 16;
  return x.f;
}
// quad_perm lane swaps on the VALU pipe (no LDS)
static __device__ __forceinline__ float qxor1(float x) {
  int r = __builtin_amdgcn_mov_dpp(__builtin_bit_cast(int, x), 0xB1, 0xF, 0xF, true);
  return __builtin_bit_cast(float, r);
}
static __device__ __forceinline__ float qxor2(float x) {
  int r = __builtin_amdgcn_mov_dpp(__builtin_bit_cast(int, x), 0x4E, 0xF, 0xF, true);
  return __builtin_bit_cast(float, r);
}

// ---------------- convert pw weights (3 layers) to bf16 ----------------
__global__ __launch_bounds__(256) void k_cvt(const float* __restrict__ src, unsigned short* __restrict__ dst,
                                             int n) {
  int i = blockIdx.x * 256 + threadIdx.x;
  if (i < n) dst[i] = f2b(src[i]);
}

// ---------------- embedding: strided conv1d (stride 8, K=16, pad 4/4) -> bf16 u[sig][t][d] ----------------
__global__ __launch_bounds__(256) void k_emb(const float* __restrict__ inp, const float* __restrict__ ew,
                                             const float* __restrict__ eb, unsigned short* __restrict__ xe) {
  int sig = blockIdx.x;
  int b = sig / MM, m = sig % MM;
  __shared__ float xs[LL];
  __shared__ float ews[DD * 17];
  __shared__ float ebs[DD];
  const float* ib = inp + (size_t)b * LL * MM + m;
  int tid = threadIdx.x;
  for (int i = tid; i < LL; i += 256) xs[i] = ib[(size_t)i * MM];
  for (int i = tid; i < DD * 16; i += 256) ews[(i >> 4) * 17 + (i & 15)] = ew[i];
  if (tid < DD) ebs[tid] = eb[tid];
  __syncthreads();
  int d0 = (tid & 15) * 8;
  for (int it = 0; it < 16; ++it) {
    int t = it * 16 + (tid >> 4);
    int l0 = t * 8 - 4;
    float acc[8];
#pragma unroll
    for (int j = 0; j < 8; ++j) acc[j] = ebs[d0 + j];
#pragma unroll
    for (int p = 0; p < 16; ++p) {
      int l = l0 + p;
      float xv = (l >= 0 && l < LL) ? xs[l] : 0.0f;
#pragma unroll
      for (int j = 0; j < 8; ++j) acc[j] += xv * ews[(d0 + j) * 17 + p];
    }
    short8 r;
#pragma unroll
    for (int j = 0; j < 8; ++j) r[j] = (short)f2b(acc[j]);
    *(short8*)(xe + (size_t)sig * 32768 + (size_t)t * 128 + d0) = r;
  }
}

// ---------------- fused block, layout [sig][t][d] ----------------
template<int UPD>
__global__ __launch_bounds__(256) void k_blk(const unsigned short* __restrict__ uin,
                                             const unsigned short* __restrict__ win,
                                             const float* __restrict__ abuf,
                                             const float* __restrict__ dww, const float* __restrict__ dwb,
                                             const unsigned short* __restrict__ pwbf,
                                             const float* __restrict__ pwb,
                                             unsigned short* __restrict__ uout,
                                             unsigned short* __restrict__ wout,
                                             float* __restrict__ sbuf) {
  __shared__ float smemf[10512];
  unsigned short* us = (unsigned short*)smemf;   // [68][136] bf16
  unsigned short* vT = us + 9248;                // [64][136] bf16
  float* dws  = smemf + 8976;
  float* dwbs = smemf + 9616;
  float* abufL= smemf + 9744;
  float* pwbL = smemf + 9872;
  float* sred = smemf + 10000;

  int sig = blockIdx.x >> 2;
  int t0 = (blockIdx.x & 3) * 64;
  int tid = threadIdx.x;
  const size_t gbase = (size_t)sig * 32768;

  for (int i = tid; i < 640; i += 256) dws[i] = dww[i];
  if (tid < 128) {
    dwbs[tid] = dwb[tid];
    pwbL[tid] = pwb[tid];
    abufL[tid] = UPD ? abuf[sig * 128 + tid] : 0.0f;
  }
  __syncthreads();

  int c8 = (tid & 15) * 8;
  float aloc[8];
#pragma unroll
  for (int j = 0; j < 8; ++j) aloc[j] = abufL[c8 + j];

  const short8 ZV = {0, 0, 0, 0, 0, 0, 0, 0};
#pragma unroll
  for (int it = 0; it < 5; ++it) {
    int idx = it * 256 + tid;
    if (idx < 1088) {
      int row = idx >> 4;
      int t = t0 - 2 + row;
      short8 u8 = ZV;
      if (t >= 0 && t < TP) {
        u8 = *(const short8*)(uin + gbase + (size_t)t * 128 + c8);
        if (UPD) {
          short8 w8 = *(const short8*)(win + gbase + (size_t)t * 128 + c8);
          short8 r;
#pragma unroll
          for (int j = 0; j < 8; ++j)
            r[j] = (short)f2b(b2f((unsigned short)u8[j]) + b2f((unsigned short)w8[j]) * aloc[j]);
          u8 = r;
          if (row >= 2 && row < 66)
            *(short8*)(uout + gbase + (size_t)(t0 + row - 2) * 128 + c8) = u8;
        }
      }
      *(short8*)(us + row * 136 + c8) = u8;
    }
  }
  __syncthreads();

  float wl[5][8], bl[8];
#pragma unroll
  for (int j = 0; j < 8; ++j) {
    bl[j] = dwbs[c8 + j];
#pragma unroll
    for (int k = 0; k < 5; ++k) wl[k][j] = dws[(c8 + j) * 5 + k];
  }
#pragma unroll
  for (int it = 0; it < 4; ++it) {
    int t = it * 16 + (tid >> 4);
    float acc[8];
#pragma unroll
    for (int j = 0; j < 8; ++j) acc[j] = bl[j];
#pragma unroll
    for (int k = 0; k < 5; ++k) {
      short8 u8 = *(const short8*)(us + (t + k) * 136 + c8);
#pragma unroll
      for (int j = 0; j < 8; ++j) acc[j] += b2f((unsigned short)u8[j]) * wl[k][j];
    }
    short8 r;
#pragma unroll
    for (int j = 0; j < 8; ++j) {
      float g = 0.5f * acc[j] * (1.0f + erff(acc[j] * 0.70710678118654752f));
      r[j] = (short)f2b(g);
    }
    *(short8*)(vT + t * 136 + c8) = r;
  }
  __syncthreads();

  int wv = tid >> 6;
  int ln = tid & 15;
  int q  = (tid >> 4) & 3;
  int tw = wv * 16;
  float4v acc[8];
#pragma unroll
  for (int et = 0; et < 8; ++et) acc[et] = (float4v){0.f, 0.f, 0.f, 0.f};
#pragma unroll
  for (int kc = 0; kc < 4; ++kc) {
    int d0 = kc * 32;
    short8 bfrag = *(const short8*)(vT + (tw + ln) * 136 + d0 + q * 8);
#pragma unroll
    for (int et = 0; et < 8; ++et) {
      short8 af = *(const short8*)(pwbf + (size_t)(et * 16 + ln) * 128 + d0 + q * 8);
      acc[et] = __builtin_amdgcn_mfma_f32_16x16x32_bf16(af, bfrag, acc[et], 0, 0, 0);
    }
  }

  int tg = t0 + tw + ln;
#pragma unroll
  for (int et = 0; et < 8; ++et) {
    int e = et * 16 + q * 4;
    float v0 = acc[et][0] + pwbL[e];
    float v1 = acc[et][1] + pwbL[e + 1];
    float v2 = acc[et][2] + pwbL[e + 2];
    float v3 = acc[et][3] + pwbL[e + 3];
    short4v st = {(short)f2b(v0), (short)f2b(v1), (short)f2b(v2), (short)f2b(v3)};
    *(short4v*)(wout + gbase + (size_t)tg * 128 + e) = st;
    float s0 = v0, s1 = v1, s2 = v2, s3 = v3;
#pragma unroll
    for (int m = 1; m <= 8; m <<= 1) {
      s0 += __shfl_xor(s0, m, 64);
      s1 += __shfl_xor(s1, m, 64);
      s2 += __shfl_xor(s2, m, 64);
      s3 += __shfl_xor(s3, m, 64);
    }
    if (ln == 0) {
      float4v sv = {s0, s1, s2, s3};
      *(float4v*)&sred[wv * 128 + e] = sv;
    }
  }
  __syncthreads();
  if (tid < 128) {
    float tot = sred[tid] + sred[128 + tid] + sred[256 + tid] + sred[384 + tid];
    atomicAdd(&sbuf[sig * 128 + tid], tot);
  }
}

// ---------------- block: SE gate ----------------
__global__ __launch_bounds__(128) void k_se(const float* __restrict__ sbuf, const float* __restrict__ w1,
                                            const float* __restrict__ b1, const float* __restrict__ w2,
                                            const float* __restrict__ b2, float* __restrict__ abuf) {
  int sig = blockIdx.x;
  __shared__ float sm[128];
  __shared__ float hh[32];
  int tid = threadIdx.x;
  sm[tid] = sbuf[sig * 128 + tid] * (1.0f / 256.0f);
  __syncthreads();
  if (tid < 32) {
    float acc = b1[tid];
    for (int d = 0; d < 128; ++d) acc += w1[tid * 128 + d] * sm[d];
    hh[tid] = fmaxf(acc, 0.0f);
  }
  __syncthreads();
  float acc = b2[tid];
#pragma unroll
  for (int r = 0; r < 32; ++r) acc += w2[tid * 32 + r] * hh[r];
  abuf[sig * 128 + tid] = 1.0f / (1.0f + expf(-acc));
}

// ---------------- final update + mean over M -> xe2[b][t][d] fp32 ----------------
__global__ __launch_bounds__(256) void k_reduce2(const unsigned short* __restrict__ u,
                                                 const unsigned short* __restrict__ w,
                                                 const float* __restrict__ abuf, float* __restrict__ xe2) {
  int i = blockIdx.x * 256 + threadIdx.x;
  int d0 = (i & 15) * 8;
  int t = (i >> 4) & 255;
  int b = i >> 12;
  float acc[8] = {0.f, 0.f, 0.f, 0.f, 0.f, 0.f, 0.f, 0.f};
#pragma unroll 4
  for (int m = 0; m < 12; ++m) {
    size_t base = ((size_t)(b * 12 + m) * 256 + t) * 128 + d0;
    short8 u8 = *(const short8*)(u + base);
    short8 w8 = *(const short8*)(w + base);
    float4 a0 = *(const float4*)&abuf[(b * 12 + m) * 128 + d0];
    float4 a1 = *(const float4*)&abuf[(b * 12 + m) * 128 + d0 + 4];
    float av[8] = {a0.x, a0.y, a0.z, a0.w, a1.x, a1.y, a1.z, a1.w};
#pragma unroll
    for (int j = 0; j < 8; ++j)
      acc[j] += b2f((unsigned short)u8[j]) + b2f((unsigned short)w8[j]) * av[j];
  }
  float* out = xe2 + (size_t)b * 32768 + (size_t)t * 128 + d0;
  float4 o0 = {acc[0] / 12.f, acc[1] / 12.f, acc[2] / 12.f, acc[3] / 12.f};
  float4 o1 = {acc[4] / 12.f, acc[5] / 12.f, acc[6] / 12.f, acc[7] / 12.f};
  *(float4*)out = o0;
  *(float4*)(out + 4) = o1;
}

// ---------------- small transpose ----------------
__global__ __launch_bounds__(256) void k_transpose(const float* __restrict__ src, float* __restrict__ dst,
                                                   int rows, int cols) {
  int i = blockIdx.x * 256 + threadIdx.x;
  if (i < rows * cols) {
    int r = i / cols, c = i % cols;
    dst[c * rows + r] = src[i];
  }
}

// ---------------- mamba: in-projection ----------------
__global__ __launch_bounds__(256) void k_inproj(const float* __restrict__ xe2, const float* __restrict__ inwT,
                                                float* __restrict__ xz) {
  int b = blockIdx.x >> 4;
  int t0 = (blockIdx.x & 15) * 16;
  __shared__ float xT[128][16];
  int tid = threadIdx.x;
  for (int idx = tid; idx < 2048; idx += 256) {
    int t = idx >> 7, d = idx & 127;
    xT[d][t] = xe2[(size_t)b * 32768 + (size_t)(t0 + t) * 128 + d];
  }
  __syncthreads();
  int eg = tid >> 1, tg = tid & 1;
  int e0 = eg * 4, ts = tg * 8;
  float acc[4][8];
#pragma unroll
  for (int j = 0; j < 4; ++j)
#pragma unroll
    for (int i = 0; i < 8; ++i) acc[j][i] = 0.0f;
#pragma unroll 4
  for (int d = 0; d < 128; ++d) {
    float4 wv = *(const float4*)&inwT[d * 512 + e0];
    float4 xa = *(const float4*)&xT[d][ts];
    float4 xb = *(const float4*)&xT[d][ts + 4];
    float xv[8] = {xa.x, xa.y, xa.z, xa.w, xb.x, xb.y, xb.z, xb.w};
    float wvv[4] = {wv.x, wv.y, wv.z, wv.w};
#pragma unroll
    for (int j = 0; j < 4; ++j)
#pragma unroll
      for (int i = 0; i < 8; ++i) acc[j][i] += wvv[j] * xv[i];
  }
#pragma unroll
  for (int i = 0; i < 8; ++i) {
    float4 o = {acc[0][i], acc[1][i], acc[2][i], acc[3][i]};
    *(float4*)&xz[(size_t)b * 256 * 512 + (size_t)(t0 + ts + i) * 512 + e0] = o;
  }
}

// ---------------- mamba: causal depthwise conv (K=4) + SiLU ----------------
__global__ __launch_bounds__(256) void k_convsilu(const float* __restrict__ xz, const float* __restrict__ cw,
                                                  const float* __restrict__ cb, float* __restrict__ xc) {
  size_t i = (size_t)blockIdx.x * 256 + threadIdx.x;
  int c = (int)(i & 255);
  int t = (int)((i >> 8) & 255);
  int b = (int)(i >> 16);
  const float* zb = xz + (size_t)b * 256 * 512 + c;
  float4 w4 = *(const float4*)&cw[c * 4];
  float wv[4] = {w4.x, w4.y, w4.z, w4.w};
  float acc = cb[c];
#pragma unroll
  for (int k = 0; k < 4; ++k) {
    int tt = t - 3 + k;
    if (tt >= 0) acc += zb[(size_t)tt * 512] * wv[k];
  }
  xc[i] = acc / (1.0f + expf(-acc));
}

// ---------------- mamba: x-projection (40 x 256) ----------------
__global__ __launch_bounds__(256) void k_xproj(const float* __restrict__ xc, const float* __restrict__ xw,
                                               float* __restrict__ dbl) {
  int b = blockIdx.x >> 3;
  int t0 = (blockIdx.x & 7) * 32;
  __shared__ float xT[256][33];
  int tid = threadIdx.x;
  for (int idx = tid; idx < 32 * 256; idx += 256) {
    int t = idx >> 8, c = idx & 255;
    xT[c][t] = xc[(size_t)b * 65536 + (size_t)(t0 + t) * 256 + c];
  }
  __syncthreads();
  int t = tid & 31, k0 = tid >> 5;
  for (int k = k0; k < 40; k += 8) {
    float acc = 0.0f;
    for (int c = 0; c < 256; ++c) acc += xw[k * 256 + c] * xT[c][t];
    dbl[(size_t)b * 256 * 40 + (size_t)(t0 + t) * 40 + k] = acc;
  }
}

// ---------------- mamba: fused dt + selective scan + y-finalize ----------------
// 512 blocks x 128 threads. Block: batch b = blk>>3, channels c0 = (blk&7)*32.
// Wave = 16 channels x (4 lanes = 4 states each). DPP quad-reduce, b128 LDS reads.
__global__ __launch_bounds__(128) void k_scan2(const float* __restrict__ dbl, const float* __restrict__ xc,
                                               const float* __restrict__ xz, const float* __restrict__ Alog,
                                               const float* __restrict__ dtw, const float* __restrict__ dtbv,
                                               const float* __restrict__ Dp, float* __restrict__ y) {
  __shared__ float ds[32][40];       // dbl chunk (dtr|B|C), shared across channels
  __shared__ float dxs[32][32][4];   // per (t, c): {dt, xc, z, pad}
  __shared__ float yl[32][32];
  __shared__ float dtwL[32][8];
  __shared__ float dtbL[32];
  __shared__ float DpL[32];

  int b = blockIdx.x >> 3;
  int c0 = (blockIdx.x & 7) * 32;
  int tid = threadIdx.x;

  for (int idx = tid; idx < 256; idx += 128) dtwL[idx >> 3][idx & 7] = dtw[(c0 + (idx >> 3)) * 8 + (idx & 7)];
  if (tid < 32) { dtbL[tid] = dtbv[c0 + tid]; DpL[tid] = Dp[c0 + tid]; }

  int lane = tid & 63;
  int wv = tid >> 6;
  int c_loc = wv * 16 + (lane >> 2);
  int c = c0 + c_loc;
  int sblk = (lane & 3) * 4;

  float4 Al = *(const float4*)&Alog[c * 16 + sblk];
  float A[4] = {-__expf(Al.x), -__expf(Al.y), -__expf(Al.z), -__expf(Al.w)};
  float h[4] = {0.f, 0.f, 0.f, 0.f};

  const float* dbp = dbl + (size_t)b * 10240;
  const float* xcp = xc + (size_t)b * 65536;
  const float* xzp = xz + (size_t)b * 131072;
  float* yp = y + (size_t)b * 65536;

  for (int chk = 0; chk < 8; ++chk) {
    int t0c = chk * 32;
    for (int idx = tid; idx < 1280; idx += 128) ((float*)ds)[idx] = dbp[t0c * 40 + idx];
    for (int idx = tid; idx < 1024; idx += 128) {
      int t = idx >> 5, cc = idx & 31;
      dxs[t][cc][1] = xcp[(size_t)(t0c + t) * 256 + c0 + cc];
      dxs[t][cc][2] = xzp[(size_t)(t0c + t) * 512 + 256 + c0 + cc];
    }
    __syncthreads();
    for (int idx = tid; idx < 1024; idx += 128) {
      int t = idx >> 5, cc = idx & 31;
      const float* dr = ds[t];
      const float* wr = dtwL[cc];
      float acc = dtbL[cc];
#pragma unroll
      for (int j = 0; j < 8; ++j) acc += wr[j] * dr[j];
      dxs[t][cc][0] = (acc > 20.0f) ? acc : __logf(1.0f + __expf(acc));
    }
    __syncthreads();
#pragma unroll 4
    for (int t = 0; t < 32; ++t) {
      float4 dx = *(const float4*)&dxs[t][c_loc][0];
      float4 Bv = *(const float4*)&ds[t][8 + sblk];
      float4 Cv = *(const float4*)&ds[t][24 + sblk];
      float dtv = dx.x;
      float bx = dtv * dx.y;
      h[0] = __expf(dtv * A[0]) * h[0] + Bv.x * bx;
      h[1] = __expf(dtv * A[1]) * h[1] + Bv.y * bx;
      h[2] = __expf(dtv * A[2]) * h[2] + Bv.z * bx;
      h[3] = __expf(dtv * A[3]) * h[3] + Bv.w * bx;
      float p = h[0] * Cv.x;
      p = fmaf(h[1], Cv.y, p);
      p = fmaf(h[2], Cv.z, p);
      p = fmaf(h[3], Cv.w, p);
      p += qxor1(p);
      p += qxor2(p);
      if ((lane & 3) == 0) yl[t][c_loc] = p;
    }
    __syncthreads();
    for (int idx = tid; idx < 1024; idx += 128) {
      int t = idx >> 5, cc = idx & 31;
      float p = yl[t][cc];
      float xcv = dxs[t][cc][1];
      float zv = dxs[t][cc][2];
      float sz = zv / (1.0f + __expf(-zv));
      yp[(size_t)(t0c + t) * 256 + c0 + cc] = (p + DpL[cc] * xcv) * sz;
    }
    __syncthreads();
  }
}

// ---------------- mamba: out-projection + residual + LayerNorm (in place on xe2) ----------------
__global__ __launch_bounds__(256) void k_outln(const float* __restrict__ y, const float* __restrict__ owT,
                                               float* __restrict__ xe2, const float* __restrict__ g,
                                               const float* __restrict__ bb) {
  int b = blockIdx.x >> 5;
  int t0 = (blockIdx.x & 31) * 8;
  __shared__ float yl[8][256];
  __shared__ float rl[8][129];
  __shared__ float mus[8], rvs[8];
  int tid = threadIdx.x;
  for (int idx = tid; idx < 8 * 256; idx += 256) {
    int t = idx >> 8, c = idx & 255;
    yl[t][c] = y[(size_t)b * 65536 + (size_t)(t0 + t) * 256 + c];
  }
  __syncthreads();
  int d = tid & 127, tg = tid >> 7;
  float acc[4] = {0.f, 0.f, 0.f, 0.f};
  for (int e = 0; e < 256; ++e) {
    float w = owT[e * 128 + d];
#pragma unroll
    for (int i = 0; i < 4; ++i) acc[i] += w * yl[tg * 4 + i][e];
  }
#pragma unroll
  for (int i = 0; i < 4; ++i) {
    int t = tg * 4 + i;
    float r = xe2[(size_t)b * 32768 + (size_t)(t0 + t) * 128 + d] + acc[i];
    rl[t][d] = r;
  }
  __syncthreads();
  int rt = tid >> 5, j = tid & 31;
  float s1 = 0.f, s2 = 0.f;
#pragma unroll
  for (int q = 0; q < 4; ++q) {
    float vv = rl[rt][j + q * 32];
    s1 += vv; s2 += vv * vv;
  }
#pragma unroll
  for (int m = 1; m <= 16; m <<= 1) {
    s1 += __shfl_xor(s1, m, 64);
    s2 += __shfl_xor(s2, m, 64);
  }
  if (j == 0) {
    float mu = s1 * (1.0f / 128.0f);
    float var = s2 * (1.0f / 128.0f) - mu * mu;
    mus[rt] = mu;
    rvs[rt] = rsqrtf(var + 1e-5f);
  }
  __syncthreads();
#pragma unroll
  for (int i = 0; i < 4; ++i) {
    int t = tg * 4 + i;
    float val = (rl[t][d] - mus[t]) * rvs[t] * g[d] + bb[d];
    xe2[(size_t)b * 32768 + (size_t)(t0 + t) * 128 + d] = val;
  }
}

// ---------------- xflat transpose ----------------
__global__ __launch_bounds__(256) void k_xflat(const float* __restrict__ xe2, float* __restrict__ out) {
  int b = blockIdx.x >> 5;
  int blk = blockIdx.x & 31;
  int t0 = (blk >> 2) * 32, d0 = (blk & 3) * 32;
  __shared__ float tile[32][33];
  int tid = threadIdx.x;
#pragma unroll
  for (int q = 0; q < 4; ++q) {
    int t = (tid >> 5) + q * 8, dd = tid & 31;
    tile[t][dd] = xe2[(size_t)b * 32768 + (size_t)(t0 + t) * 128 + d0 + dd];
  }
  __syncthreads();
#pragma unroll
  for (int q = 0; q < 4; ++q) {
    int dd = (tid >> 5) + q * 8, t = tid & 31;
    out[(size_t)b * 32768 + (size_t)(d0 + dd) * 256 + t0 + t] = tile[t][dd];
  }
}

// ---------------- final FC ----------------
__global__ __launch_bounds__(256) void k_fc(const float* __restrict__ xflat, const float* __restrict__ fw,
                                            const float* __restrict__ fb, float* __restrict__ pred) {
  int b = blockIdx.x;
  int tid = threadIdx.x;
  float acc[18];
#pragma unroll
  for (int c = 0; c < 18; ++c) acc[c] = 0.0f;
  const float* xb = xflat + (size_t)b * 32768;
  for (int i = tid * 4; i < 32768; i += 1024) {
    float4 xv = *(const float4*)&xb[i];
#pragma unroll
    for (int c = 0; c < 18; ++c) {
      float4 wv = *(const float4*)&fw[(size_t)c * 32768 + i];
      acc[c] += xv.x * wv.x + xv.y * wv.y + xv.z * wv.z + xv.w * wv.w;
    }
  }
  __shared__ float red[256];
  for (int c = 0; c < 18; ++c) {
    red[tid] = acc[c];
    __syncthreads();
    for (int off = 128; off > 0; off >>= 1) {
      if (tid < off) red[tid] += red[tid + off];
      __syncthreads();
    }
    if (tid == 0) pred[b * 18 + c] = red[0] + fb[c];
    __syncthreads();
  }
}

extern "C" void kernel_launch(void* const* d_in, const int* in_sizes, int n_in,
                              void* d_out, int out_size, void* d_ws, size_t ws_size,
                              hipStream_t stream) {
  (void)in_sizes; (void)n_in; (void)out_size; (void)ws_size;
  const float* inp    = (const float*)d_in[0];
  const float* emb_w  = (const float*)d_in[1];
  const float* emb_b  = (const float*)d_in[2];
  const float* dw_w   = (const float*)d_in[3];
  const float* dw_b   = (const float*)d_in[4];
  const float* pw_w   = (const float*)d_in[5];
  const float* pw_b   = (const float*)d_in[6];
  const float* se_w1  = (const float*)d_in[7];
  const float* se_b1  = (const float*)d_in[8];
  const float* se_w2  = (const float*)d_in[9];
  const float* se_b2  = (const float*)d_in[10];
  const float* in_w   = (const float*)d_in[11];
  const float* conv_w = (const float*)d_in[12];
  const float* conv_b = (const float*)d_in[13];
  const float* xp_w   = (const float*)d_in[14];
  const float* dt_w   = (const float*)d_in[15];
  const float* dt_b   = (const float*)d_in[16];
  const float* Alog   = (const float*)d_in[17];
  const float* Dp     = (const float*)d_in[18];
  const float* out_w  = (const float*)d_in[19];
  const float* ln_g   = (const float*)d_in[20];
  const float* ln_b   = (const float*)d_in[21];
  const float* fc_w   = (const float*)d_in[22];
  const float* fc_b   = (const float*)d_in[23];

  char* ws = (char*)d_ws;
  unsigned short* U0 = (unsigned short*)(ws);
  unsigned short* W0 = (unsigned short*)(ws + 50331648);
  unsigned short* U1 = (unsigned short*)(ws + 100663296);
  unsigned short* W1 = (unsigned short*)(ws + 150994944);
  float* sbuf = (float*)(ws + 201326592);
  float* abuf = sbuf + 98304;
  float* xz  = (float*)(ws);
  float* xc  = (float*)(ws + 33554432);
  float* yb  = (float*)(ws + 50331648);
  float* xe2 = (float*)(ws + 100663296);
  float* dbl = (float*)(ws + 150994944);
  float* inwT= (float*)(ws + 153616384);
  float* owT = (float*)(ws + 153878528);

  float* xflat = (float*)d_out;
  float* pred  = xflat + (size_t)64 * 32768;
  unsigned short* pwbf = (unsigned short*)d_out;  // scratch until k_xflat overwrites

  k_cvt<<<192, 256, 0, stream>>>(pw_w, pwbf, 49152);
  k_emb<<<768, 256, 0, stream>>>(inp, emb_w, emb_b, U0);

  hipMemsetAsync(sbuf, 0, 98304 * sizeof(float), stream);
  k_blk<0><<<3072, 256, 0, stream>>>(U0, U0, abuf, dw_w, dw_b, pwbf, pw_b, U0, W0, sbuf);
  k_se<<<768, 128, 0, stream>>>(sbuf, se_w1, se_b1, se_w2, se_b2, abuf);
  hipMemsetAsync(sbuf, 0, 98304 * sizeof(float), stream);
  k_blk<1><<<3072, 256, 0, stream>>>(U0, W0, abuf, dw_w + 640, dw_b + 128, pwbf + 16384, pw_b + 128,
                                     U1, W1, sbuf);
  k_se<<<768, 128, 0, stream>>>(sbuf, se_w1 + 4096, se_b1 + 32, se_w2 + 4096, se_b2 + 128, abuf);
  hipMemsetAsync(sbuf, 0, 98304 * sizeof(float), stream);
  k_blk<1><<<3072, 256, 0, stream>>>(U1, W1, abuf, dw_w + 1280, dw_b + 256, pwbf + 32768, pw_b + 256,
                                     U0, W0, sbuf);
  k_se<<<768, 128, 0, stream>>>(sbuf, se_w1 + 8192, se_b1 + 64, se_w2 + 8192, se_b2 + 256, abuf);

  k_reduce2<<<1024, 256, 0, stream>>>(U0, W0, abuf, xe2);

  for (int i = 0; i < 2; ++i) {
    k_transpose<<<256, 256, 0, stream>>>(in_w + i * 65536, inwT, 512, 128);
    k_transpose<<<128, 256, 0, stream>>>(out_w + i * 32768, owT, 128, 256);
    k_inproj<<<1024, 256, 0, stream>>>(xe2, inwT, xz);
    k_convsilu<<<16384, 256, 0, stream>>>(xz, conv_w + i * 1024, conv_b + i * 256, xc);
    k_xproj<<<512, 256, 0, stream>>>(xc, xp_w + i * 10240, dbl);
    k_scan2<<<512, 128, 0, stream>>>(dbl, xc, xz, Alog + i * 4096,
                                     dt_w + i * 2048, dt_b + i * 256, Dp + i * 256, yb);
    k_outln<<<2048, 256, 0, stream>>>(yb, owT, xe2, ln_g + i * 128, ln_b + i * 128);
  }

  k_xflat<<<2048, 256, 0, stream>>>(xe2, xflat);
  k_fc<<<64, 256, 0, stream>>>(xflat, fc_w, fc_b, pred);
}